// Round 12
// baseline (438.147 us; speedup 1.0000x reference)
//
#include <hip/hip_runtime.h>
#include <math.h>

#define BB 4
#define NN 512
#define DIMX 384
#define HH 8
#define PDD 64
#define JC 64
#define PWPAD 66   // f2-aligned rows; scalar col reads and f2 row-slices both min-cost banks

static constexpr float EPSV = 1e-8f;
static constexpr float SCALAR_SCALE = 0.14433756729740643f;  // (3*16)^-0.5
static constexpr float POINT_SCALE  = 0.1360827634879543f;   // (3*4*4.5)^-0.5
static constexpr float PAIR_SCALE   = 0.5773502691896258f;   // 3^-0.5

// ---------------- rope table ----------------
__global__ void k_rope(float* __restrict__ cos_t, float* __restrict__ sin_t) {
    int n = blockIdx.x * blockDim.x + threadIdx.x;
    if (n >= NN) return;
#pragma unroll
    for (int i = 0; i < 8; ++i) {
        float invf = powf(10000.0f, -(float)i / 8.0f);
        float f = (float)n * invf;
        cos_t[n * 8 + i] = cosf(f);
        sin_t[n * 8 + i] = sinf(f);
    }
}

// ---------------- projections + transforms (column-half split) ----------------
__global__ __launch_bounds__(256) void k_proj(
    const float* __restrict__ x, const float* __restrict__ rot,
    const float* __restrict__ trans, const int* __restrict__ pos_ids,
    const float* __restrict__ Wq_s, const float* __restrict__ Wk_s, const float* __restrict__ Wv_s,
    const float* __restrict__ Wq_p, const float* __restrict__ Wk_p, const float* __restrict__ Wv_p,
    const float* __restrict__ cos_t, const float* __restrict__ sin_t,
    float* __restrict__ qsg, float* __restrict__ qpg, float* __restrict__ qqg,
    float4* __restrict__ kst, float* __restrict__ kpt, float* __restrict__ kkg,
    float4* __restrict__ vst, float* __restrict__ vpt)
{
    __shared__ float xl[8][DIMX];
    __shared__ float raw[8][384];
    const int t = threadIdx.x;
    const int tile = blockIdx.x >> 1;
    const int half = blockIdx.x & 1;
    const int tok0 = tile * 8;

    {
        const float4* xg = (const float4*)(x + (size_t)tok0 * DIMX);
        float4* xl4 = (float4*)&xl[0][0];
#pragma unroll
        for (int k = 0; k < 3; ++k) xl4[t + 256 * k] = xg[t + 256 * k];
    }
    __syncthreads();

    const int tok = t >> 5, l = t & 31;
    {
        float4 acc[3];
        const float* wb[3];
        int st[3];
#pragma unroll
        for (int m = 0; m < 3; ++m) {
            int f = l + 32 * m + 96 * half;
            const float* w; int out, c;
            if (f < 32)       { w = Wq_s; out = 128; c = 4 * f; }
            else if (f < 64)  { w = Wk_s; out = 128; c = 4 * f - 128; }
            else if (f < 96)  { w = Wv_s; out = 128; c = 4 * f - 256; }
            else if (f < 120) { w = Wq_p; out = 96;  c = 4 * f - 384; }
            else if (f < 144) { w = Wk_p; out = 96;  c = 4 * f - 480; }
            else              { w = Wv_p; out = 192; c = 4 * f - 576; }
            wb[m] = w + c; st[m] = out;
            acc[m] = make_float4(0.f, 0.f, 0.f, 0.f);
        }
        for (int dd = 0; dd < DIMX; ++dd) {
            float xv = xl[tok][dd];
#pragma unroll
            for (int m = 0; m < 3; ++m) {
                float4 wv = *(const float4*)(wb[m] + (size_t)dd * st[m]);
                acc[m].x = fmaf(xv, wv.x, acc[m].x);
                acc[m].y = fmaf(xv, wv.y, acc[m].y);
                acc[m].z = fmaf(xv, wv.z, acc[m].z);
                acc[m].w = fmaf(xv, wv.w, acc[m].w);
            }
        }
#pragma unroll
        for (int m = 0; m < 3; ++m)
            *(float4*)&raw[tok][4 * (l + 32 * m)] = acc[m];
    }
    __syncthreads();

    const int h = l >> 2, q = l & 3;
    const int n_g = tok0 + tok;
    const int b = n_g / NN;
    const int nloc = n_g - b * NN;
    const int bh = b * HH + h;
    const size_t rowi = (size_t)bh * NN + nloc;

    if (half == 0) {
        const int pos = pos_ids[n_g];
        float qv[4], kv[4], vv[4];
#pragma unroll
        for (int dd0 = 0; dd0 < 4; ++dd0) {
            int dd = q * 4 + dd0;
            int i8 = dd & 7;
            float c = cos_t[pos * 8 + i8], s = sin_t[pos * 8 + i8];
            float xq = raw[tok][h * 16 + dd];
            float rq = (dd < 8) ? -raw[tok][h * 16 + dd + 8] : raw[tok][h * 16 + dd - 8];
            qv[dd0] = fmaf(xq, c, rq * s);
            float xk = raw[tok][128 + h * 16 + dd];
            float rk = (dd < 8) ? -raw[tok][128 + h * 16 + dd + 8] : raw[tok][128 + h * 16 + dd - 8];
            kv[dd0] = fmaf(xk, c, rk * s);
            vv[dd0] = raw[tok][256 + h * 16 + dd];
        }
        *(float4*)&qsg[rowi * 16 + q * 4] = make_float4(qv[0], qv[1], qv[2], qv[3]);
        kst[(size_t)bh * 2048 + q * 512 + nloc] = make_float4(kv[0], kv[1], kv[2], kv[3]);
        vst[(size_t)bh * 2048 + q * 512 + nloc] = make_float4(vv[0], vv[1], vv[2], vv[3]);
    } else {
        const float* Rm = rot + (size_t)n_g * 9;
        const float trv[3] = {trans[n_g * 3 + 0], trans[n_g * 3 + 1], trans[n_g * 3 + 2]};
        float qqp = 0.f, kkp = 0.f;
        {
            float pc[3], kc[3];
#pragma unroll
            for (int c = 0; c < 3; ++c) {
                pc[c] = raw[tok][h * 12 + q * 3 + c];
                kc[c] = raw[tok][96 + h * 12 + q * 3 + c];
            }
#pragma unroll
            for (int r = 0; r < 3; ++r) {
                float vq = trv[r], vk = trv[r];
#pragma unroll
                for (int c = 0; c < 3; ++c) {
                    vq = fmaf(pc[c], Rm[c * 3 + r], vq);
                    vk = fmaf(kc[c], Rm[c * 3 + r], vk);
                }
                qpg[rowi * 12 + q * 3 + r] = vq;
                int d = q * 3 + r;   // 0..11
                kpt[(size_t)bh * 6144 + (d >> 2) * 2048 + nloc * 4 + (d & 3)] = vk;
                qqp = fmaf(vq, vq, qqp);
                kkp = fmaf(vk, vk, kkp);
            }
        }
        qqp += __shfl_xor(qqp, 1); qqp += __shfl_xor(qqp, 2);
        kkp += __shfl_xor(kkp, 1); kkp += __shfl_xor(kkp, 2);
        if (q == 0) { qqg[rowi] = qqp; kkg[rowi] = kkp; }
#pragma unroll
        for (int pp = 0; pp < 2; ++pp) {
            int p = q + 4 * pp;
            float pc[3];
#pragma unroll
            for (int c = 0; c < 3; ++c) pc[c] = raw[tok][192 + h * 24 + p * 3 + c];
#pragma unroll
            for (int r = 0; r < 3; ++r) {
                float v = trv[r];
#pragma unroll
                for (int c = 0; c < 3; ++c) v = fmaf(pc[c], Rm[c * 3 + r], v);
                int d = p * 3 + r;   // 0..23
                vpt[(size_t)bh * 12288 + (d >> 2) * 2048 + nloc * 4 + (d & 3)] = v;
            }
        }
    }
}

// ---------------- fused attention: 512 threads, wave = head, lane = j ----------------
// r10 structure + early-issued K/V loads (latency drains under staging barriers) and
// scalarized W_pair reads (s_load via readfirstlane-uniform index, no LDS).
__global__ __launch_bounds__(512, 2) void k_attn(
    const float* __restrict__ pairw,
    const float* __restrict__ rot, const float* __restrict__ trans,
    const float* __restrict__ Wpair, const float* __restrict__ bpair,
    const float* __restrict__ pweights,
    const float* __restrict__ qsg, const float* __restrict__ qpg, const float* __restrict__ qqg,
    const float4* __restrict__ kst, const float4* __restrict__ kpt, const float* __restrict__ kkg,
    const float4* __restrict__ vst, const float4* __restrict__ vpt,
    float* __restrict__ feats)
{
    __shared__ float pwt[JC][PWPAD];      // pairwise tile (16.9KB)
    __shared__ float parts[8][HH][JC];    // [slice][head][j] bias partials (16KB)
    __shared__ float plds[HH][JC];
    __shared__ float qsh[HH][16];
    __shared__ float qph[HH][12];
    __shared__ float qqh[HH];

    const int t = threadIdx.x;
    const int bi = blockIdx.x;
    const int b = bi >> 9;
    const int h = t >> 6, l = t & 63;  // wave = head, lane = j-in-chunk
    const int hs = __builtin_amdgcn_readfirstlane(h);  // wave-uniform -> scalar loads of W

    const int bh = b * HH + h;
    const size_t rowq = (size_t)bh * NN + (bi & 511);
    if (l < 16) qsh[h][l] = qsg[rowq * 16 + l];
    if (l < 12) qph[h][l] = qpg[rowq * 12 + l];
    if (l == 0) qqh[h] = qqg[rowq];

    const float coefP = -0.5f * log1pf(__expf(pweights[h])) * POINT_SCALE;
    const float bp_h = bpair[h];

    const float4* ksb = kst + (size_t)bh * 2048;   // [4][512] f4
    const float4* vsb = vst + (size_t)bh * 2048;
    const float4* kpb = kpt + (size_t)bh * 1536;   // [3][512] f4
    const float4* vpb = vpt + (size_t)bh * 3072;   // [6][512] f4
    const float*  kkb = kkg + (size_t)bh * 512;

    const float4* pwsrc = (const float4*)(pairw + (size_t)bi * NN * PDD);

    float m = -3.0e38f, lsum = 0.f;
    float ap0 = 0.f, ap1 = 0.f, ap2 = 0.f, ap3 = 0.f;
    float ascd[16], aptd[24];
#pragma unroll
    for (int d = 0; d < 16; ++d) ascd[d] = 0.f;
#pragma unroll
    for (int d = 0; d < 24; ++d) aptd[d] = 0.f;

    for (int c = 0; c < NN / JC; ++c) {
        const int j = c * JC + l;
        // ---- issue ALL global K/V loads early: latency drains during staging+barriers ----
        const float4 k0 = ksb[j], k1 = ksb[512 + j], k2 = ksb[1024 + j], k3 = ksb[1536 + j];
        const float4 P0 = kpb[j], P1 = kpb[512 + j], P2 = kpb[1024 + j];
        const float kkv = kkb[j];
        const float4 v0 = vsb[j], v1 = vsb[512 + j], v2 = vsb[1024 + j], v3 = vsb[1536 + j];
        const float4 w0g = vpb[j],        w1g = vpb[512 + j],  w2g = vpb[1024 + j];
        const float4 w3g = vpb[1536 + j], w4g = vpb[2048 + j], w5g = vpb[2560 + j];
        __syncthreads();   // A: prev chunk's pwt/parts reads done (also drains loads)
        {   // stage pairwise chunk (f2 LDS writes)
            const float4* s = pwsrc + (size_t)c * 1024;
            float4 vA = s[t], vB = s[t + 512];
            int jA = t >> 4, dA = (t & 15) * 4;
            *(float2*)&pwt[jA][dA]     = make_float2(vA.x, vA.y);
            *(float2*)&pwt[jA][dA + 2] = make_float2(vA.z, vA.w);
            int f2i = t + 512, jB = f2i >> 4, dB = (f2i & 15) * 4;
            *(float2*)&pwt[jB][dB]     = make_float2(vB.x, vB.y);
            *(float2*)&pwt[jB][dB + 2] = make_float2(vB.z, vB.w);
        }
        __syncthreads();   // B: pwt ready
        {   // bias partials: slice = h, row = l; W via wave-uniform scalar loads
            float2 u0 = *(const float2*)&pwt[l][8 * h + 0];
            float2 u1 = *(const float2*)&pwt[l][8 * h + 2];
            float2 u2 = *(const float2*)&pwt[l][8 * h + 4];
            float2 u3 = *(const float2*)&pwt[l][8 * h + 6];
            float pv[8] = {u0.x, u0.y, u1.x, u1.y, u2.x, u2.y, u3.x, u3.y};
            float ps[8];
#pragma unroll
            for (int hh = 0; hh < 8; ++hh) ps[hh] = 0.f;
#pragma unroll
            for (int k = 0; k < 8; ++k) {
                const float4 w0 = *(const float4*)&Wpair[(8 * hs + k) * 8];
                const float4 w1 = *(const float4*)&Wpair[(8 * hs + k) * 8 + 4];
                const float pk = pv[k];
                ps[0] = fmaf(pk, w0.x, ps[0]); ps[1] = fmaf(pk, w0.y, ps[1]);
                ps[2] = fmaf(pk, w0.z, ps[2]); ps[3] = fmaf(pk, w0.w, ps[3]);
                ps[4] = fmaf(pk, w1.x, ps[4]); ps[5] = fmaf(pk, w1.y, ps[5]);
                ps[6] = fmaf(pk, w1.z, ps[6]); ps[7] = fmaf(pk, w1.w, ps[7]);
            }
#pragma unroll
            for (int hh = 0; hh < 8; ++hh) parts[h][hh][l] = ps[hh];
        }
        __syncthreads();   // C: partials ready
        float bs = 0.f;
#pragma unroll
        for (int s2 = 0; s2 < 8; ++s2) bs += parts[s2][h][l];
        const float bias = (bs + bp_h) * PAIR_SCALE;
        // ---- logit (uses early-loaded k/P regs) ----
        float lg;
        {
            const float4 qs0 = *(const float4*)&qsh[h][0];
            const float4 qs1 = *(const float4*)&qsh[h][4];
            const float4 qs2 = *(const float4*)&qsh[h][8];
            const float4 qs3 = *(const float4*)&qsh[h][12];
            float d0 = 0.f, d1 = 0.f;
            d0 = fmaf(qs0.x, k0.x, d0); d0 = fmaf(qs0.y, k0.y, d0);
            d0 = fmaf(qs0.z, k0.z, d0); d0 = fmaf(qs0.w, k0.w, d0);
            d1 = fmaf(qs1.x, k1.x, d1); d1 = fmaf(qs1.y, k1.y, d1);
            d1 = fmaf(qs1.z, k1.z, d1); d1 = fmaf(qs1.w, k1.w, d1);
            d0 = fmaf(qs2.x, k2.x, d0); d0 = fmaf(qs2.y, k2.y, d0);
            d0 = fmaf(qs2.z, k2.z, d0); d0 = fmaf(qs2.w, k2.w, d0);
            d1 = fmaf(qs3.x, k3.x, d1); d1 = fmaf(qs3.y, k3.y, d1);
            d1 = fmaf(qs3.z, k3.z, d1); d1 = fmaf(qs3.w, k3.w, d1);
            const float4 qp0 = *(const float4*)&qph[h][0];
            const float4 qp1 = *(const float4*)&qph[h][4];
            const float4 qp2 = *(const float4*)&qph[h][8];
            float e0 = 0.f, e1 = 0.f;
            e0 = fmaf(qp0.x, P0.x, e0); e0 = fmaf(qp0.y, P0.y, e0);
            e0 = fmaf(qp0.z, P0.z, e0); e0 = fmaf(qp0.w, P0.w, e0);
            e1 = fmaf(qp1.x, P1.x, e1); e1 = fmaf(qp1.y, P1.y, e1);
            e1 = fmaf(qp1.z, P1.z, e1); e1 = fmaf(qp1.w, P1.w, e1);
            e0 = fmaf(qp2.x, P2.x, e0); e0 = fmaf(qp2.y, P2.y, e0);
            e0 = fmaf(qp2.z, P2.z, e0); e0 = fmaf(qp2.w, P2.w, e0);
            float dist = qqh[h] + kkv - 2.f * (e0 + e1);
            lg = fmaf(d0 + d1, SCALAR_SCALE, fmaf(coefP, dist, bias));
        }
        // ---- online softmax across the 64-lane wave, defer-rescale (T13) ----
        float cmax = lg;
#pragma unroll
        for (int off = 32; off > 0; off >>= 1) cmax = fmaxf(cmax, __shfl_xor(cmax, off));
        if (cmax > m + 6.f) {
            const float sc = __expf(m - cmax);
            m = cmax; lsum *= sc;
            ap0 *= sc; ap1 *= sc; ap2 *= sc; ap3 *= sc;
#pragma unroll
            for (int d = 0; d < 16; ++d) ascd[d] *= sc;
#pragma unroll
            for (int d = 0; d < 24; ++d) aptd[d] *= sc;
        }
        const float p = __expf(lg - m);
        float psum = p;
#pragma unroll
        for (int off = 32; off > 0; off >>= 1) psum += __shfl_xor(psum, off);
        lsum += psum;
        plds[h][l] = p;
        // ---- pair accumulation first (LDS-only), giving v/vp loads extra window ----
#pragma unroll
        for (int u = 0; u < 16; ++u) {
            float4 p4 = *(const float4*)&plds[h][4 * u];
            ap0 = fmaf(p4.x, pwt[4 * u + 0][l], ap0);
            ap1 = fmaf(p4.y, pwt[4 * u + 1][l], ap1);
            ap2 = fmaf(p4.z, pwt[4 * u + 2][l], ap2);
            ap3 = fmaf(p4.w, pwt[4 * u + 3][l], ap3);
        }
        // ---- v accumulation (consumes early-loaded regs) ----
        {
            ascd[0]  = fmaf(p, v0.x, ascd[0]);  ascd[1]  = fmaf(p, v0.y, ascd[1]);
            ascd[2]  = fmaf(p, v0.z, ascd[2]);  ascd[3]  = fmaf(p, v0.w, ascd[3]);
            ascd[4]  = fmaf(p, v1.x, ascd[4]);  ascd[5]  = fmaf(p, v1.y, ascd[5]);
            ascd[6]  = fmaf(p, v1.z, ascd[6]);  ascd[7]  = fmaf(p, v1.w, ascd[7]);
            ascd[8]  = fmaf(p, v2.x, ascd[8]);  ascd[9]  = fmaf(p, v2.y, ascd[9]);
            ascd[10] = fmaf(p, v2.z, ascd[10]); ascd[11] = fmaf(p, v2.w, ascd[11]);
            ascd[12] = fmaf(p, v3.x, ascd[12]); ascd[13] = fmaf(p, v3.y, ascd[13]);
            ascd[14] = fmaf(p, v3.z, ascd[14]); ascd[15] = fmaf(p, v3.w, ascd[15]);
            aptd[0]  = fmaf(p, w0g.x, aptd[0]);  aptd[1]  = fmaf(p, w0g.y, aptd[1]);
            aptd[2]  = fmaf(p, w0g.z, aptd[2]);  aptd[3]  = fmaf(p, w0g.w, aptd[3]);
            aptd[4]  = fmaf(p, w1g.x, aptd[4]);  aptd[5]  = fmaf(p, w1g.y, aptd[5]);
            aptd[6]  = fmaf(p, w1g.z, aptd[6]);  aptd[7]  = fmaf(p, w1g.w, aptd[7]);
            aptd[8]  = fmaf(p, w2g.x, aptd[8]);  aptd[9]  = fmaf(p, w2g.y, aptd[9]);
            aptd[10] = fmaf(p, w2g.z, aptd[10]); aptd[11] = fmaf(p, w2g.w, aptd[11]);
            aptd[12] = fmaf(p, w3g.x, aptd[12]); aptd[13] = fmaf(p, w3g.y, aptd[13]);
            aptd[14] = fmaf(p, w3g.z, aptd[14]); aptd[15] = fmaf(p, w3g.w, aptd[15]);
            aptd[16] = fmaf(p, w4g.x, aptd[16]); aptd[17] = fmaf(p, w4g.y, aptd[17]);
            aptd[18] = fmaf(p, w4g.z, aptd[18]); aptd[19] = fmaf(p, w4g.w, aptd[19]);
            aptd[20] = fmaf(p, w5g.x, aptd[20]); aptd[21] = fmaf(p, w5g.y, aptd[21]);
            aptd[22] = fmaf(p, w5g.z, aptd[22]); aptd[23] = fmaf(p, w5g.w, aptd[23]);
        }
    }

    // ---- epilogue: butterfly-reduce j-partials across 64 lanes ----
#pragma unroll
    for (int off = 32; off > 0; off >>= 1) {
#pragma unroll
        for (int d = 0; d < 16; ++d) ascd[d] += __shfl_xor(ascd[d], off);
#pragma unroll
        for (int d = 0; d < 24; ++d) aptd[d] += __shfl_xor(aptd[d], off);
    }
    const float ap = (ap0 + ap1) + (ap2 + ap3);
    const float inv_l = 1.f / lsum;
    float* fb = feats + (size_t)bi * 896;
    if (l < 16) fb[h * 16 + l] = ascd[l] * inv_l;             // m_scalar
    fb[384 + h * 64 + l] = ap * inv_l;                        // m_pair (lane owns d=l)
    const float tr0 = trans[bi * 3 + 0], tr1 = trans[bi * 3 + 1], tr2 = trans[bi * 3 + 2];
    if (l < 24) {
        const int pp = l / 3, r = l - pp * 3;
        const float c0 = aptd[pp * 3 + 0] * inv_l - tr0;
        const float c1 = aptd[pp * 3 + 1] * inv_l - tr1;
        const float c2 = aptd[pp * 3 + 2] * inv_l - tr2;
        const float* Rm = rot + (size_t)bi * 9 + r * 3;       // R[r][c]
        fb[128 + h * 24 + pp * 3 + r] = fmaf(c0, Rm[0], fmaf(c1, Rm[1], c2 * Rm[2]));
    }
    if (l < 8) {
        const float c0 = aptd[l * 3 + 0] * inv_l - tr0;
        const float c1 = aptd[l * 3 + 1] * inv_l - tr1;
        const float c2 = aptd[l * 3 + 2] * inv_l - tr2;
        fb[320 + h * 8 + l] = sqrtf(fmaf(c0, c0, fmaf(c1, c1, fmaf(c2, c2, EPSV))));
    }
}

// ---------------- output projection: 4 tokens x 192-col half per block (r7-proven) ----------------
__global__ __launch_bounds__(256) void k_out(
    const float* __restrict__ feats, const float* __restrict__ Wout,
    const float* __restrict__ bout, float* __restrict__ out)
{
    __shared__ float fl[4][896];
    const int t = threadIdx.x;
    const int tile = blockIdx.x >> 1;
    const int half = blockIdx.x & 1;
    const int tok0 = tile * 4;
    {
        const float4* src = (const float4*)(feats + (size_t)tok0 * 896);
        float4* dst = (float4*)&fl[0][0];
        dst[t] = src[t];
        dst[t + 256] = src[t + 256];
        dst[t + 512] = src[t + 512];
        if (t < 128) dst[t + 768] = src[t + 768];   // 896 float4 total
    }
    __syncthreads();
    const int tok = t >> 6, l = t & 63;
    const int c0 = 192 * half;
    float acc0 = 0.f, acc1 = 0.f, acc2 = 0.f;
#pragma unroll 8
    for (int dd = 0; dd < 896; ++dd) {
        float fv = fl[tok][dd];
        const float* wr = Wout + (size_t)dd * 384 + c0;
        acc0 = fmaf(fv, wr[l], acc0);
        acc1 = fmaf(fv, wr[l + 64], acc1);
        acc2 = fmaf(fv, wr[l + 128], acc2);
    }
    float* ob = out + (size_t)(tok0 + tok) * 384 + c0;
    ob[l]       = acc0 + bout[c0 + l];
    ob[l + 64]  = acc1 + bout[c0 + l + 64];
    ob[l + 128] = acc2 + bout[c0 + l + 128];
}

extern "C" void kernel_launch(void* const* d_in, const int* in_sizes, int n_in,
                              void* d_out, int out_size, void* d_ws, size_t ws_size,
                              hipStream_t stream) {
    const float* x        = (const float*)d_in[0];
    const float* pairw    = (const float*)d_in[1];
    const float* rot      = (const float*)d_in[2];
    const float* trans    = (const float*)d_in[3];
    const int*   pos      = (const int*)d_in[4];
    const float* Wq_s     = (const float*)d_in[6];
    const float* Wk_s     = (const float*)d_in[7];
    const float* Wv_s     = (const float*)d_in[8];
    const float* Wq_p     = (const float*)d_in[9];
    const float* Wk_p     = (const float*)d_in[10];
    const float* Wv_p     = (const float*)d_in[11];
    const float* pweights = (const float*)d_in[12];
    const float* Wpair    = (const float*)d_in[13];
    const float* bpair    = (const float*)d_in[14];
    const float* Wout     = (const float*)d_in[15];
    const float* bout     = (const float*)d_in[16];
    float* out = (float*)d_out;

    float* ws = (float*)d_ws;
    float* cos_t = ws;   ws += 4096;
    float* sin_t = ws;   ws += 4096;
    float* qsg = ws;     ws += BB * HH * NN * 16;
    float* qpg = ws;     ws += BB * HH * NN * 12;
    float* qqg = ws;     ws += BB * HH * NN;
    float4* kst = (float4*)ws; ws += BB * HH * NN * 16;   // [bh][4][N] f4
    float* kpt = ws;     ws += BB * HH * NN * 12;         // [bh][3][N] f4
    float* kkg = ws;     ws += BB * HH * NN;
    float4* vst = (float4*)ws; ws += BB * HH * NN * 16;   // [bh][4][N] f4
    float* vpt = ws;     ws += BB * HH * NN * 24;         // [bh][6][N] f4
    float* feats = ws;   ws += BB * NN * 896;

    k_rope<<<2, 256, 0, stream>>>(cos_t, sin_t);
    k_proj<<<(BB * NN) / 8 * 2, 256, 0, stream>>>(x, rot, trans, pos,
        Wq_s, Wk_s, Wv_s, Wq_p, Wk_p, Wv_p, cos_t, sin_t,
        qsg, qpg, qqg, kst, kpt, kkg, vst, vpt);
    k_attn<<<BB * NN, 512, 0, stream>>>(pairw, rot, trans, Wpair, bpair, pweights,
        qsg, qpg, qqg, kst, (const float4*)kpt, kkg, vst, (const float4*)vpt, feats);
    k_out<<<(BB * NN) / 4 * 2, 256, 0, stream>>>(feats, Wout, bout, out);

    (void)in_sizes; (void)n_in; (void)out_size; (void)ws_size;
}

// Round 13
// 373.849 us; speedup vs baseline: 1.1720x; 1.1720x over previous
//
#include <hip/hip_runtime.h>
#include <math.h>

#define BB 4
#define NN 512
#define DIMX 384
#define HH 8
#define PDD 64
#define JC 64
#define PWPAD 66   // f2-aligned rows; scalar col reads and f2 row-slices both min-cost banks

static constexpr float EPSV = 1e-8f;
static constexpr float SCALAR_SCALE = 0.14433756729740643f;  // (3*16)^-0.5
static constexpr float POINT_SCALE  = 0.1360827634879543f;   // (3*4*4.5)^-0.5
static constexpr float PAIR_SCALE   = 0.5773502691896258f;   // 3^-0.5

// ---------------- rope table ----------------
__global__ void k_rope(float* __restrict__ cos_t, float* __restrict__ sin_t) {
    int n = blockIdx.x * blockDim.x + threadIdx.x;
    if (n >= NN) return;
#pragma unroll
    for (int i = 0; i < 8; ++i) {
        float invf = powf(10000.0f, -(float)i / 8.0f);
        float f = (float)n * invf;
        cos_t[n * 8 + i] = cosf(f);
        sin_t[n * 8 + i] = sinf(f);
    }
}

// ---------------- projections + transforms (column-half split) ----------------
__global__ __launch_bounds__(256) void k_proj(
    const float* __restrict__ x, const float* __restrict__ rot,
    const float* __restrict__ trans, const int* __restrict__ pos_ids,
    const float* __restrict__ Wq_s, const float* __restrict__ Wk_s, const float* __restrict__ Wv_s,
    const float* __restrict__ Wq_p, const float* __restrict__ Wk_p, const float* __restrict__ Wv_p,
    const float* __restrict__ cos_t, const float* __restrict__ sin_t,
    float* __restrict__ qsg, float* __restrict__ qpg, float* __restrict__ qqg,
    float4* __restrict__ kst, float* __restrict__ kpt, float* __restrict__ kkg,
    float4* __restrict__ vst, float* __restrict__ vpt)
{
    __shared__ float xl[8][DIMX];
    __shared__ float raw[8][384];
    const int t = threadIdx.x;
    const int tile = blockIdx.x >> 1;
    const int half = blockIdx.x & 1;
    const int tok0 = tile * 8;

    {
        const float4* xg = (const float4*)(x + (size_t)tok0 * DIMX);
        float4* xl4 = (float4*)&xl[0][0];
#pragma unroll
        for (int k = 0; k < 3; ++k) xl4[t + 256 * k] = xg[t + 256 * k];
    }
    __syncthreads();

    const int tok = t >> 5, l = t & 31;
    {
        float4 acc[3];
        const float* wb[3];
        int st[3];
#pragma unroll
        for (int m = 0; m < 3; ++m) {
            int f = l + 32 * m + 96 * half;
            const float* w; int out, c;
            if (f < 32)       { w = Wq_s; out = 128; c = 4 * f; }
            else if (f < 64)  { w = Wk_s; out = 128; c = 4 * f - 128; }
            else if (f < 96)  { w = Wv_s; out = 128; c = 4 * f - 256; }
            else if (f < 120) { w = Wq_p; out = 96;  c = 4 * f - 384; }
            else if (f < 144) { w = Wk_p; out = 96;  c = 4 * f - 480; }
            else              { w = Wv_p; out = 192; c = 4 * f - 576; }
            wb[m] = w + c; st[m] = out;
            acc[m] = make_float4(0.f, 0.f, 0.f, 0.f);
        }
        for (int dd = 0; dd < DIMX; ++dd) {
            float xv = xl[tok][dd];
#pragma unroll
            for (int m = 0; m < 3; ++m) {
                float4 wv = *(const float4*)(wb[m] + (size_t)dd * st[m]);
                acc[m].x = fmaf(xv, wv.x, acc[m].x);
                acc[m].y = fmaf(xv, wv.y, acc[m].y);
                acc[m].z = fmaf(xv, wv.z, acc[m].z);
                acc[m].w = fmaf(xv, wv.w, acc[m].w);
            }
        }
#pragma unroll
        for (int m = 0; m < 3; ++m)
            *(float4*)&raw[tok][4 * (l + 32 * m)] = acc[m];
    }
    __syncthreads();

    const int h = l >> 2, q = l & 3;
    const int n_g = tok0 + tok;
    const int b = n_g / NN;
    const int nloc = n_g - b * NN;
    const int bh = b * HH + h;
    const size_t rowi = (size_t)bh * NN + nloc;

    if (half == 0) {
        const int pos = pos_ids[n_g];
        float qv[4], kv[4], vv[4];
#pragma unroll
        for (int dd0 = 0; dd0 < 4; ++dd0) {
            int dd = q * 4 + dd0;
            int i8 = dd & 7;
            float c = cos_t[pos * 8 + i8], s = sin_t[pos * 8 + i8];
            float xq = raw[tok][h * 16 + dd];
            float rq = (dd < 8) ? -raw[tok][h * 16 + dd + 8] : raw[tok][h * 16 + dd - 8];
            qv[dd0] = fmaf(xq, c, rq * s);
            float xk = raw[tok][128 + h * 16 + dd];
            float rk = (dd < 8) ? -raw[tok][128 + h * 16 + dd + 8] : raw[tok][128 + h * 16 + dd - 8];
            kv[dd0] = fmaf(xk, c, rk * s);
            vv[dd0] = raw[tok][256 + h * 16 + dd];
        }
        *(float4*)&qsg[rowi * 16 + q * 4] = make_float4(qv[0], qv[1], qv[2], qv[3]);
        kst[(size_t)bh * 2048 + q * 512 + nloc] = make_float4(kv[0], kv[1], kv[2], kv[3]);
        vst[(size_t)bh * 2048 + q * 512 + nloc] = make_float4(vv[0], vv[1], vv[2], vv[3]);
    } else {
        const float* Rm = rot + (size_t)n_g * 9;
        const float trv[3] = {trans[n_g * 3 + 0], trans[n_g * 3 + 1], trans[n_g * 3 + 2]};
        float qqp = 0.f, kkp = 0.f;
        {
            float pc[3], kc[3];
#pragma unroll
            for (int c = 0; c < 3; ++c) {
                pc[c] = raw[tok][h * 12 + q * 3 + c];
                kc[c] = raw[tok][96 + h * 12 + q * 3 + c];
            }
#pragma unroll
            for (int r = 0; r < 3; ++r) {
                float vq = trv[r], vk = trv[r];
#pragma unroll
                for (int c = 0; c < 3; ++c) {
                    vq = fmaf(pc[c], Rm[c * 3 + r], vq);
                    vk = fmaf(kc[c], Rm[c * 3 + r], vk);
                }
                qpg[rowi * 12 + q * 3 + r] = vq;
                int d = q * 3 + r;   // 0..11
                kpt[(size_t)bh * 6144 + (d >> 2) * 2048 + nloc * 4 + (d & 3)] = vk;
                qqp = fmaf(vq, vq, qqp);
                kkp = fmaf(vk, vk, kkp);
            }
        }
        qqp += __shfl_xor(qqp, 1); qqp += __shfl_xor(qqp, 2);
        kkp += __shfl_xor(kkp, 1); kkp += __shfl_xor(kkp, 2);
        if (q == 0) { qqg[rowi] = qqp; kkg[rowi] = kkp; }
#pragma unroll
        for (int pp = 0; pp < 2; ++pp) {
            int p = q + 4 * pp;
            float pc[3];
#pragma unroll
            for (int c = 0; c < 3; ++c) pc[c] = raw[tok][192 + h * 24 + p * 3 + c];
#pragma unroll
            for (int r = 0; r < 3; ++r) {
                float v = trv[r];
#pragma unroll
                for (int c = 0; c < 3; ++c) v = fmaf(pc[c], Rm[c * 3 + r], v);
                int d = p * 3 + r;   // 0..23
                vpt[(size_t)bh * 12288 + (d >> 2) * 2048 + nloc * 4 + (d & 3)] = v;
            }
        }
    }
}

// ---------------- fused attention: 512 threads, wave = head, lane = j ----------------
// Verbatim round-10 k_attn (proven 256 us): in-loop slice-parallel bias (Wl in LDS),
// q in LDS, single pw buffer, 3 barriers/chunk, (512,2).
__global__ __launch_bounds__(512, 2) void k_attn(
    const float* __restrict__ pairw,
    const float* __restrict__ rot, const float* __restrict__ trans,
    const float* __restrict__ Wpair, const float* __restrict__ bpair,
    const float* __restrict__ pweights,
    const float* __restrict__ qsg, const float* __restrict__ qpg, const float* __restrict__ qqg,
    const float4* __restrict__ kst, const float4* __restrict__ kpt, const float* __restrict__ kkg,
    const float4* __restrict__ vst, const float4* __restrict__ vpt,
    float* __restrict__ feats)
{
    __shared__ float pwt[JC][PWPAD];      // pairwise tile (16.9KB)
    __shared__ float parts[8][HH][JC];    // [slice][head][j] bias partials (16KB)
    __shared__ float Wl[512];             // W_pair [d][h] row-major
    __shared__ float plds[HH][JC];
    __shared__ float qsh[HH][16];
    __shared__ float qph[HH][12];
    __shared__ float qqh[HH];

    const int t = threadIdx.x;
    const int bi = blockIdx.x;
    const int b = bi >> 9;
    const int h = t >> 6, l = t & 63;  // wave = head, lane = j-in-chunk

    Wl[t] = Wpair[t];

    const int bh = b * HH + h;
    const size_t rowq = (size_t)bh * NN + (bi & 511);
    if (l < 16) qsh[h][l] = qsg[rowq * 16 + l];
    if (l < 12) qph[h][l] = qpg[rowq * 12 + l];
    if (l == 0) qqh[h] = qqg[rowq];

    const float coefP = -0.5f * log1pf(__expf(pweights[h])) * POINT_SCALE;
    const float bp_h = bpair[h];

    const float4* ksb = kst + (size_t)bh * 2048;   // [4][512] f4
    const float4* vsb = vst + (size_t)bh * 2048;
    const float4* kpb = kpt + (size_t)bh * 1536;   // [3][512] f4
    const float4* vpb = vpt + (size_t)bh * 3072;   // [6][512] f4
    const float*  kkb = kkg + (size_t)bh * 512;

    const float4* pwsrc = (const float4*)(pairw + (size_t)bi * NN * PDD);

    float m = -3.0e38f, lsum = 0.f;
    float ap0 = 0.f, ap1 = 0.f, ap2 = 0.f, ap3 = 0.f;
    float ascd[16], aptd[24];
#pragma unroll
    for (int d = 0; d < 16; ++d) ascd[d] = 0.f;
#pragma unroll
    for (int d = 0; d < 24; ++d) aptd[d] = 0.f;

    for (int c = 0; c < NN / JC; ++c) {
        __syncthreads();   // A: prev chunk's pwt/parts reads done
        {   // stage pairwise chunk (f2 LDS writes, min-slot banks)
            const float4* s = pwsrc + (size_t)c * 1024;
            float4 vA = s[t], vB = s[t + 512];
            int jA = t >> 4, dA = (t & 15) * 4;
            *(float2*)&pwt[jA][dA]     = make_float2(vA.x, vA.y);
            *(float2*)&pwt[jA][dA + 2] = make_float2(vA.z, vA.w);
            int f2i = t + 512, jB = f2i >> 4, dB = (f2i & 15) * 4;
            *(float2*)&pwt[jB][dB]     = make_float2(vB.x, vB.y);
            *(float2*)&pwt[jB][dB + 2] = make_float2(vB.z, vB.w);
        }
        __syncthreads();   // B: pwt ready
        {   // bias partials: slice = h, row = l
            float2 u0 = *(const float2*)&pwt[l][8 * h + 0];
            float2 u1 = *(const float2*)&pwt[l][8 * h + 2];
            float2 u2 = *(const float2*)&pwt[l][8 * h + 4];
            float2 u3 = *(const float2*)&pwt[l][8 * h + 6];
            float pv0 = u0.x, pv1 = u0.y, pv2 = u1.x, pv3 = u1.y;
            float pv4 = u2.x, pv5 = u2.y, pv6 = u3.x, pv7 = u3.y;
            float ps[8];
#pragma unroll
            for (int hh = 0; hh < 8; ++hh) ps[hh] = 0.f;
#pragma unroll
            for (int k = 0; k < 8; ++k) {
                float pk = (k == 0) ? pv0 : (k == 1) ? pv1 : (k == 2) ? pv2 : (k == 3) ? pv3
                         : (k == 4) ? pv4 : (k == 5) ? pv5 : (k == 6) ? pv6 : pv7;
                const float4 w0 = *(const float4*)&Wl[(8 * h + k) * 8];
                const float4 w1 = *(const float4*)&Wl[(8 * h + k) * 8 + 4];
                ps[0] = fmaf(pk, w0.x, ps[0]); ps[1] = fmaf(pk, w0.y, ps[1]);
                ps[2] = fmaf(pk, w0.z, ps[2]); ps[3] = fmaf(pk, w0.w, ps[3]);
                ps[4] = fmaf(pk, w1.x, ps[4]); ps[5] = fmaf(pk, w1.y, ps[5]);
                ps[6] = fmaf(pk, w1.z, ps[6]); ps[7] = fmaf(pk, w1.w, ps[7]);
            }
#pragma unroll
            for (int hh = 0; hh < 8; ++hh) parts[h][hh][l] = ps[hh];
        }
        __syncthreads();   // C: partials ready
        float bs = 0.f;
#pragma unroll
        for (int s2 = 0; s2 < 8; ++s2) bs += parts[s2][h][l];
        const float bias = (bs + bp_h) * PAIR_SCALE;
        // ---- logit (f4-packed d-major loads, all stride-1 coalesced) ----
        const int j = c * JC + l;
        float lg;
        {
            const float4 qs0 = *(const float4*)&qsh[h][0];
            const float4 qs1 = *(const float4*)&qsh[h][4];
            const float4 qs2 = *(const float4*)&qsh[h][8];
            const float4 qs3 = *(const float4*)&qsh[h][12];
            float4 k0 = ksb[j], k1 = ksb[512 + j], k2 = ksb[1024 + j], k3 = ksb[1536 + j];
            float d0 = 0.f, d1 = 0.f;
            d0 = fmaf(qs0.x, k0.x, d0); d0 = fmaf(qs0.y, k0.y, d0);
            d0 = fmaf(qs0.z, k0.z, d0); d0 = fmaf(qs0.w, k0.w, d0);
            d1 = fmaf(qs1.x, k1.x, d1); d1 = fmaf(qs1.y, k1.y, d1);
            d1 = fmaf(qs1.z, k1.z, d1); d1 = fmaf(qs1.w, k1.w, d1);
            d0 = fmaf(qs2.x, k2.x, d0); d0 = fmaf(qs2.y, k2.y, d0);
            d0 = fmaf(qs2.z, k2.z, d0); d0 = fmaf(qs2.w, k2.w, d0);
            d1 = fmaf(qs3.x, k3.x, d1); d1 = fmaf(qs3.y, k3.y, d1);
            d1 = fmaf(qs3.z, k3.z, d1); d1 = fmaf(qs3.w, k3.w, d1);
            const float4 qp0 = *(const float4*)&qph[h][0];
            const float4 qp1 = *(const float4*)&qph[h][4];
            const float4 qp2 = *(const float4*)&qph[h][8];
            float4 P0 = kpb[j], P1 = kpb[512 + j], P2 = kpb[1024 + j];
            float e0 = 0.f, e1 = 0.f;
            e0 = fmaf(qp0.x, P0.x, e0); e0 = fmaf(qp0.y, P0.y, e0);
            e0 = fmaf(qp0.z, P0.z, e0); e0 = fmaf(qp0.w, P0.w, e0);
            e1 = fmaf(qp1.x, P1.x, e1); e1 = fmaf(qp1.y, P1.y, e1);
            e1 = fmaf(qp1.z, P1.z, e1); e1 = fmaf(qp1.w, P1.w, e1);
            e0 = fmaf(qp2.x, P2.x, e0); e0 = fmaf(qp2.y, P2.y, e0);
            e0 = fmaf(qp2.z, P2.z, e0); e0 = fmaf(qp2.w, P2.w, e0);
            float dist = qqh[h] + kkb[j] - 2.f * (e0 + e1);
            lg = fmaf(d0 + d1, SCALAR_SCALE, fmaf(coefP, dist, bias));
        }
        // ---- online softmax across the 64-lane wave, defer-rescale (T13) ----
        float cmax = lg;
#pragma unroll
        for (int off = 32; off > 0; off >>= 1) cmax = fmaxf(cmax, __shfl_xor(cmax, off));
        if (cmax > m + 6.f) {          // wave-uniform branch
            const float sc = __expf(m - cmax);
            m = cmax; lsum *= sc;
            ap0 *= sc; ap1 *= sc; ap2 *= sc; ap3 *= sc;
#pragma unroll
            for (int d = 0; d < 16; ++d) ascd[d] *= sc;
#pragma unroll
            for (int d = 0; d < 24; ++d) aptd[d] *= sc;
        }
        const float p = __expf(lg - m);
        float psum = p;
#pragma unroll
        for (int off = 32; off > 0; off >>= 1) psum += __shfl_xor(psum, off);
        lsum += psum;
        plds[h][l] = p;
        // ---- v accumulation (f4-packed coalesced loads) ----
        {
            float4 v0 = vsb[j], v1 = vsb[512 + j], v2 = vsb[1024 + j], v3 = vsb[1536 + j];
            ascd[0]  = fmaf(p, v0.x, ascd[0]);  ascd[1]  = fmaf(p, v0.y, ascd[1]);
            ascd[2]  = fmaf(p, v0.z, ascd[2]);  ascd[3]  = fmaf(p, v0.w, ascd[3]);
            ascd[4]  = fmaf(p, v1.x, ascd[4]);  ascd[5]  = fmaf(p, v1.y, ascd[5]);
            ascd[6]  = fmaf(p, v1.z, ascd[6]);  ascd[7]  = fmaf(p, v1.w, ascd[7]);
            ascd[8]  = fmaf(p, v2.x, ascd[8]);  ascd[9]  = fmaf(p, v2.y, ascd[9]);
            ascd[10] = fmaf(p, v2.z, ascd[10]); ascd[11] = fmaf(p, v2.w, ascd[11]);
            ascd[12] = fmaf(p, v3.x, ascd[12]); ascd[13] = fmaf(p, v3.y, ascd[13]);
            ascd[14] = fmaf(p, v3.z, ascd[14]); ascd[15] = fmaf(p, v3.w, ascd[15]);
#pragma unroll
            for (int g = 0; g < 6; ++g) {
                float4 w = vpb[g * 512 + j];
                aptd[4 * g + 0] = fmaf(p, w.x, aptd[4 * g + 0]);
                aptd[4 * g + 1] = fmaf(p, w.y, aptd[4 * g + 1]);
                aptd[4 * g + 2] = fmaf(p, w.z, aptd[4 * g + 2]);
                aptd[4 * g + 3] = fmaf(p, w.w, aptd[4 * g + 3]);
            }
        }
        // ---- pair accumulation: lane owns dim d=l; col reads 2-way (free); 4 chains ----
#pragma unroll
        for (int u = 0; u < 16; ++u) {
            float4 p4 = *(const float4*)&plds[h][4 * u];
            ap0 = fmaf(p4.x, pwt[4 * u + 0][l], ap0);
            ap1 = fmaf(p4.y, pwt[4 * u + 1][l], ap1);
            ap2 = fmaf(p4.z, pwt[4 * u + 2][l], ap2);
            ap3 = fmaf(p4.w, pwt[4 * u + 3][l], ap3);
        }
    }

    // ---- epilogue: butterfly-reduce j-partials across 64 lanes ----
#pragma unroll
    for (int off = 32; off > 0; off >>= 1) {
#pragma unroll
        for (int d = 0; d < 16; ++d) ascd[d] += __shfl_xor(ascd[d], off);
#pragma unroll
        for (int d = 0; d < 24; ++d) aptd[d] += __shfl_xor(aptd[d], off);
    }
    const float ap = (ap0 + ap1) + (ap2 + ap3);
    const float inv_l = 1.f / lsum;
    float* fb = feats + (size_t)bi * 896;
    if (l < 16) fb[h * 16 + l] = ascd[l] * inv_l;             // m_scalar
    fb[384 + h * 64 + l] = ap * inv_l;                        // m_pair (lane owns d=l)
    const float tr0 = trans[bi * 3 + 0], tr1 = trans[bi * 3 + 1], tr2 = trans[bi * 3 + 2];
    if (l < 24) {
        const int pp = l / 3, r = l - pp * 3;
        const float c0 = aptd[pp * 3 + 0] * inv_l - tr0;
        const float c1 = aptd[pp * 3 + 1] * inv_l - tr1;
        const float c2 = aptd[pp * 3 + 2] * inv_l - tr2;
        const float* Rm = rot + (size_t)bi * 9 + r * 3;       // R[r][c]
        fb[128 + h * 24 + pp * 3 + r] = fmaf(c0, Rm[0], fmaf(c1, Rm[1], c2 * Rm[2]));
    }
    if (l < 8) {
        const float c0 = aptd[l * 3 + 0] * inv_l - tr0;
        const float c1 = aptd[l * 3 + 1] * inv_l - tr1;
        const float c2 = aptd[l * 3 + 2] * inv_l - tr2;
        fb[320 + h * 8 + l] = sqrtf(fmaf(c0, c0, fmaf(c1, c1, fmaf(c2, c2, EPSV))));
    }
}

// ---------------- output projection: 4 tokens x 192-col half per block (r7-proven) ----------------
__global__ __launch_bounds__(256) void k_out(
    const float* __restrict__ feats, const float* __restrict__ Wout,
    const float* __restrict__ bout, float* __restrict__ out)
{
    __shared__ float fl[4][896];
    const int t = threadIdx.x;
    const int tile = blockIdx.x >> 1;
    const int half = blockIdx.x & 1;
    const int tok0 = tile * 4;
    {
        const float4* src = (const float4*)(feats + (size_t)tok0 * 896);
        float4* dst = (float4*)&fl[0][0];
        dst[t] = src[t];
        dst[t + 256] = src[t + 256];
        dst[t + 512] = src[t + 512];
        if (t < 128) dst[t + 768] = src[t + 768];   // 896 float4 total
    }
    __syncthreads();
    const int tok = t >> 6, l = t & 63;
    const int c0 = 192 * half;
    float acc0 = 0.f, acc1 = 0.f, acc2 = 0.f;
#pragma unroll 8
    for (int dd = 0; dd < 896; ++dd) {
        float fv = fl[tok][dd];
        const float* wr = Wout + (size_t)dd * 384 + c0;
        acc0 = fmaf(fv, wr[l], acc0);
        acc1 = fmaf(fv, wr[l + 64], acc1);
        acc2 = fmaf(fv, wr[l + 128], acc2);
    }
    float* ob = out + (size_t)(tok0 + tok) * 384 + c0;
    ob[l]       = acc0 + bout[c0 + l];
    ob[l + 64]  = acc1 + bout[c0 + l + 64];
    ob[l + 128] = acc2 + bout[c0 + l + 128];
}

extern "C" void kernel_launch(void* const* d_in, const int* in_sizes, int n_in,
                              void* d_out, int out_size, void* d_ws, size_t ws_size,
                              hipStream_t stream) {
    const float* x        = (const float*)d_in[0];
    const float* pairw    = (const float*)d_in[1];
    const float* rot      = (const float*)d_in[2];
    const float* trans    = (const float*)d_in[3];
    const int*   pos      = (const int*)d_in[4];
    const float* Wq_s     = (const float*)d_in[6];
    const float* Wk_s     = (const float*)d_in[7];
    const float* Wv_s     = (const float*)d_in[8];
    const float* Wq_p     = (const float*)d_in[9];
    const float* Wk_p     = (const float*)d_in[10];
    const float* Wv_p     = (const float*)d_in[11];
    const float* pweights = (const float*)d_in[12];
    const float* Wpair    = (const float*)d_in[13];
    const float* bpair    = (const float*)d_in[14];
    const float* Wout     = (const float*)d_in[15];
    const float* bout     = (const float*)d_in[16];
    float* out = (float*)d_out;

    float* ws = (float*)d_ws;
    float* cos_t = ws;   ws += 4096;
    float* sin_t = ws;   ws += 4096;
    float* qsg = ws;     ws += BB * HH * NN * 16;
    float* qpg = ws;     ws += BB * HH * NN * 12;
    float* qqg = ws;     ws += BB * HH * NN;
    float4* kst = (float4*)ws; ws += BB * HH * NN * 16;   // [bh][4][N] f4
    float* kpt = ws;     ws += BB * HH * NN * 12;         // [bh][3][N] f4
    float* kkg = ws;     ws += BB * HH * NN;
    float4* vst = (float4*)ws; ws += BB * HH * NN * 16;   // [bh][4][N] f4
    float* vpt = ws;     ws += BB * HH * NN * 24;         // [bh][6][N] f4
    float* feats = ws;   ws += BB * NN * 896;

    k_rope<<<2, 256, 0, stream>>>(cos_t, sin_t);
    k_proj<<<(BB * NN) / 8 * 2, 256, 0, stream>>>(x, rot, trans, pos,
        Wq_s, Wk_s, Wv_s, Wq_p, Wk_p, Wv_p, cos_t, sin_t,
        qsg, qpg, qqg, kst, kpt, kkg, vst, vpt);
    k_attn<<<BB * NN, 512, 0, stream>>>(pairw, rot, trans, Wpair, bpair, pweights,
        qsg, qpg, qqg, kst, (const float4*)kpt, kkg, vst, (const float4*)vpt, feats);
    k_out<<<(BB * NN) / 4 * 2, 256, 0, stream>>>(feats, Wout, bout, out);

    (void)in_sizes; (void)n_in; (void)out_size; (void)ws_size;
}

// Round 14
// 358.588 us; speedup vs baseline: 1.2219x; 1.0426x over previous
//
#include <hip/hip_runtime.h>
#include <math.h>

#define BB 4
#define NN 512
#define DIMX 384
#define HH 8
#define PDD 64
#define JC 64

static constexpr float EPSV = 1e-8f;
static constexpr float SCALAR_SCALE = 0.14433756729740643f;  // (3*16)^-0.5
static constexpr float POINT_SCALE  = 0.1360827634879543f;   // (3*4*4.5)^-0.5
static constexpr float PAIR_SCALE   = 0.5773502691896258f;   // 3^-0.5

static __device__ __forceinline__ unsigned pack_bf16_rn(float a, float b) {
    unsigned ua = (__float_as_uint(a) + 0x8000u) >> 16;
    unsigned ub = (__float_as_uint(b) + 0x8000u) & 0xffff0000u;
    return ua | ub;
}

// ---------------- rope table ----------------
__global__ void k_rope(float* __restrict__ cos_t, float* __restrict__ sin_t) {
    int n = blockIdx.x * blockDim.x + threadIdx.x;
    if (n >= NN) return;
#pragma unroll
    for (int i = 0; i < 8; ++i) {
        float invf = powf(10000.0f, -(float)i / 8.0f);
        float f = (float)n * invf;
        cos_t[n * 8 + i] = cosf(f);
        sin_t[n * 8 + i] = sinf(f);
    }
}

// ---------------- projections + transforms (column-half split) ----------------
__global__ __launch_bounds__(256) void k_proj(
    const float* __restrict__ x, const float* __restrict__ rot,
    const float* __restrict__ trans, const int* __restrict__ pos_ids,
    const float* __restrict__ Wq_s, const float* __restrict__ Wk_s, const float* __restrict__ Wv_s,
    const float* __restrict__ Wq_p, const float* __restrict__ Wk_p, const float* __restrict__ Wv_p,
    const float* __restrict__ cos_t, const float* __restrict__ sin_t,
    float* __restrict__ qsg, float* __restrict__ qpg, float* __restrict__ qqg,
    float4* __restrict__ kst, float* __restrict__ kpt, float* __restrict__ kkg,
    float4* __restrict__ vst, float* __restrict__ vpt)
{
    __shared__ float xl[8][DIMX];
    __shared__ float raw[8][384];
    const int t = threadIdx.x;
    const int tile = blockIdx.x >> 1;
    const int half = blockIdx.x & 1;
    const int tok0 = tile * 8;

    {
        const float4* xg = (const float4*)(x + (size_t)tok0 * DIMX);
        float4* xl4 = (float4*)&xl[0][0];
#pragma unroll
        for (int k = 0; k < 3; ++k) xl4[t + 256 * k] = xg[t + 256 * k];
    }
    __syncthreads();

    const int tok = t >> 5, l = t & 31;
    {
        float4 acc[3];
        const float* wb[3];
        int st[3];
#pragma unroll
        for (int m = 0; m < 3; ++m) {
            int f = l + 32 * m + 96 * half;
            const float* w; int out, c;
            if (f < 32)       { w = Wq_s; out = 128; c = 4 * f; }
            else if (f < 64)  { w = Wk_s; out = 128; c = 4 * f - 128; }
            else if (f < 96)  { w = Wv_s; out = 128; c = 4 * f - 256; }
            else if (f < 120) { w = Wq_p; out = 96;  c = 4 * f - 384; }
            else if (f < 144) { w = Wk_p; out = 96;  c = 4 * f - 480; }
            else              { w = Wv_p; out = 192; c = 4 * f - 576; }
            wb[m] = w + c; st[m] = out;
            acc[m] = make_float4(0.f, 0.f, 0.f, 0.f);
        }
        for (int dd = 0; dd < DIMX; ++dd) {
            float xv = xl[tok][dd];
#pragma unroll
            for (int m = 0; m < 3; ++m) {
                float4 wv = *(const float4*)(wb[m] + (size_t)dd * st[m]);
                acc[m].x = fmaf(xv, wv.x, acc[m].x);
                acc[m].y = fmaf(xv, wv.y, acc[m].y);
                acc[m].z = fmaf(xv, wv.z, acc[m].z);
                acc[m].w = fmaf(xv, wv.w, acc[m].w);
            }
        }
#pragma unroll
        for (int m = 0; m < 3; ++m)
            *(float4*)&raw[tok][4 * (l + 32 * m)] = acc[m];
    }
    __syncthreads();

    const int h = l >> 2, q = l & 3;
    const int n_g = tok0 + tok;
    const int b = n_g / NN;
    const int nloc = n_g - b * NN;
    const int bh = b * HH + h;
    const size_t rowi = (size_t)bh * NN + nloc;

    if (half == 0) {
        const int pos = pos_ids[n_g];
        float qv[4], kv[4], vv[4];
#pragma unroll
        for (int dd0 = 0; dd0 < 4; ++dd0) {
            int dd = q * 4 + dd0;
            int i8 = dd & 7;
            float c = cos_t[pos * 8 + i8], s = sin_t[pos * 8 + i8];
            float xq = raw[tok][h * 16 + dd];
            float rq = (dd < 8) ? -raw[tok][h * 16 + dd + 8] : raw[tok][h * 16 + dd - 8];
            qv[dd0] = fmaf(xq, c, rq * s);
            float xk = raw[tok][128 + h * 16 + dd];
            float rk = (dd < 8) ? -raw[tok][128 + h * 16 + dd + 8] : raw[tok][128 + h * 16 + dd - 8];
            kv[dd0] = fmaf(xk, c, rk * s);
            vv[dd0] = raw[tok][256 + h * 16 + dd];
        }
        *(float4*)&qsg[rowi * 16 + q * 4] = make_float4(qv[0], qv[1], qv[2], qv[3]);
        kst[(size_t)bh * 2048 + q * 512 + nloc] = make_float4(kv[0], kv[1], kv[2], kv[3]);
        vst[(size_t)bh * 2048 + q * 512 + nloc] = make_float4(vv[0], vv[1], vv[2], vv[3]);
    } else {
        const float* Rm = rot + (size_t)n_g * 9;
        const float trv[3] = {trans[n_g * 3 + 0], trans[n_g * 3 + 1], trans[n_g * 3 + 2]};
        float qqp = 0.f, kkp = 0.f;
        {
            float pc[3], kc[3];
#pragma unroll
            for (int c = 0; c < 3; ++c) {
                pc[c] = raw[tok][h * 12 + q * 3 + c];
                kc[c] = raw[tok][96 + h * 12 + q * 3 + c];
            }
#pragma unroll
            for (int r = 0; r < 3; ++r) {
                float vq = trv[r], vk = trv[r];
#pragma unroll
                for (int c = 0; c < 3; ++c) {
                    vq = fmaf(pc[c], Rm[c * 3 + r], vq);
                    vk = fmaf(kc[c], Rm[c * 3 + r], vk);
                }
                qpg[rowi * 12 + q * 3 + r] = vq;
                int d = q * 3 + r;   // 0..11
                kpt[(size_t)bh * 6144 + (d >> 2) * 2048 + nloc * 4 + (d & 3)] = vk;
                qqp = fmaf(vq, vq, qqp);
                kkp = fmaf(vk, vk, kkp);
            }
        }
        qqp += __shfl_xor(qqp, 1); qqp += __shfl_xor(qqp, 2);
        kkp += __shfl_xor(kkp, 1); kkp += __shfl_xor(kkp, 2);
        if (q == 0) { qqg[rowi] = qqp; kkg[rowi] = kkp; }
#pragma unroll
        for (int pp = 0; pp < 2; ++pp) {
            int p = q + 4 * pp;
            float pc[3];
#pragma unroll
            for (int c = 0; c < 3; ++c) pc[c] = raw[tok][192 + h * 24 + p * 3 + c];
#pragma unroll
            for (int r = 0; r < 3; ++r) {
                float v = trv[r];
#pragma unroll
                for (int c = 0; c < 3; ++c) v = fmaf(pc[c], Rm[c * 3 + r], v);
                int d = p * 3 + r;   // 0..23
                vpt[(size_t)bh * 12288 + (d >> 2) * 2048 + nloc * 4 + (d & 3)] = v;
            }
        }
    }
}

// ---------------- fused attention: 512 threads, wave = head, lane = j ----------------
// r13 structure with the pw tile bf16 j-PACKED: pwt_pj[j2][d] = (bf16 pw[2j2][d], bf16 pw[2j2+1][d]).
// pair-accum column reads 64->32 (each read yields 2 j), bias row reads 4 uint2, tile 8.25KB.
__global__ __launch_bounds__(512, 2) void k_attn(
    const float* __restrict__ pairw,
    const float* __restrict__ rot, const float* __restrict__ trans,
    const float* __restrict__ Wpair, const float* __restrict__ bpair,
    const float* __restrict__ pweights,
    const float* __restrict__ qsg, const float* __restrict__ qpg, const float* __restrict__ qqg,
    const float4* __restrict__ kst, const float4* __restrict__ kpt, const float* __restrict__ kkg,
    const float4* __restrict__ vst, const float4* __restrict__ vpt,
    float* __restrict__ feats)
{
    __shared__ unsigned pwt_pj[32][66];   // bf16-packed pw tile (8.25KB), pad-66: 2-way banks
    __shared__ float parts[8][HH][JC];    // [slice][head][j] bias partials (16KB)
    __shared__ float Wl[512];             // W_pair [d][h] row-major
    __shared__ float plds[HH][JC];
    __shared__ float qsh[HH][16];
    __shared__ float qph[HH][12];
    __shared__ float qqh[HH];

    const int t = threadIdx.x;
    const int bi = blockIdx.x;
    const int b = bi >> 9;
    const int h = t >> 6, l = t & 63;  // wave = head, lane = j-in-chunk

    Wl[t] = Wpair[t];

    const int bh = b * HH + h;
    const size_t rowq = (size_t)bh * NN + (bi & 511);
    if (l < 16) qsh[h][l] = qsg[rowq * 16 + l];
    if (l < 12) qph[h][l] = qpg[rowq * 12 + l];
    if (l == 0) qqh[h] = qqg[rowq];

    const float coefP = -0.5f * log1pf(__expf(pweights[h])) * POINT_SCALE;
    const float bp_h = bpair[h];

    const float4* ksb = kst + (size_t)bh * 2048;   // [4][512] f4
    const float4* vsb = vst + (size_t)bh * 2048;
    const float4* kpb = kpt + (size_t)bh * 1536;   // [3][512] f4
    const float4* vpb = vpt + (size_t)bh * 3072;   // [6][512] f4
    const float*  kkb = kkg + (size_t)bh * 512;

    const float4* pwsrc = (const float4*)(pairw + (size_t)bi * NN * PDD);

    float m = -3.0e38f, lsum = 0.f;
    float ap0 = 0.f, ap1 = 0.f, ap2 = 0.f, ap3 = 0.f;
    float ascd[16], aptd[24];
#pragma unroll
    for (int d = 0; d < 16; ++d) ascd[d] = 0.f;
#pragma unroll
    for (int d = 0; d < 24; ++d) aptd[d] = 0.f;

    for (int c = 0; c < NN / JC; ++c) {
        __syncthreads();   // A: prev chunk's pwt_pj/parts reads done
        {   // stage + bf16-pack pairwise chunk: thread owns (j2 = t>>4, d4 = (t&15)*4)
            const int j2 = t >> 4, q4 = t & 15;
            float4 va = pwsrc[(size_t)c * 1024 + (size_t)(2 * j2) * 16 + q4];
            float4 vb = pwsrc[(size_t)c * 1024 + (size_t)(2 * j2 + 1) * 16 + q4];
            uint2 w01 = make_uint2(pack_bf16_rn(va.x, vb.x), pack_bf16_rn(va.y, vb.y));
            uint2 w23 = make_uint2(pack_bf16_rn(va.z, vb.z), pack_bf16_rn(va.w, vb.w));
            *(uint2*)&pwt_pj[j2][q4 * 4]     = w01;
            *(uint2*)&pwt_pj[j2][q4 * 4 + 2] = w23;
        }
        __syncthreads();   // B: pwt_pj ready
        {   // bias partials: slice = h, row j = l (packed row l>>1, half l&1)
            const int j2l = l >> 1;
            const bool hi = (l & 1) != 0;
            uint2 q0 = *(const uint2*)&pwt_pj[j2l][8 * h + 0];
            uint2 q1 = *(const uint2*)&pwt_pj[j2l][8 * h + 2];
            uint2 q2 = *(const uint2*)&pwt_pj[j2l][8 * h + 4];
            uint2 q3 = *(const uint2*)&pwt_pj[j2l][8 * h + 6];
            unsigned vv[8] = {q0.x, q0.y, q1.x, q1.y, q2.x, q2.y, q3.x, q3.y};
            float pv[8];
#pragma unroll
            for (int k = 0; k < 8; ++k)
                pv[k] = __uint_as_float(hi ? (vv[k] & 0xffff0000u) : (vv[k] << 16));
            float ps[8];
#pragma unroll
            for (int hh = 0; hh < 8; ++hh) ps[hh] = 0.f;
#pragma unroll
            for (int k = 0; k < 8; ++k) {
                const float pk = pv[k];
                const float4 w0 = *(const float4*)&Wl[(8 * h + k) * 8];
                const float4 w1 = *(const float4*)&Wl[(8 * h + k) * 8 + 4];
                ps[0] = fmaf(pk, w0.x, ps[0]); ps[1] = fmaf(pk, w0.y, ps[1]);
                ps[2] = fmaf(pk, w0.z, ps[2]); ps[3] = fmaf(pk, w0.w, ps[3]);
                ps[4] = fmaf(pk, w1.x, ps[4]); ps[5] = fmaf(pk, w1.y, ps[5]);
                ps[6] = fmaf(pk, w1.z, ps[6]); ps[7] = fmaf(pk, w1.w, ps[7]);
            }
#pragma unroll
            for (int hh = 0; hh < 8; ++hh) parts[h][hh][l] = ps[hh];
        }
        __syncthreads();   // C: partials ready
        float bs = 0.f;
#pragma unroll
        for (int s2 = 0; s2 < 8; ++s2) bs += parts[s2][h][l];
        const float bias = (bs + bp_h) * PAIR_SCALE;
        // ---- logit (f4-packed d-major loads, all stride-1 coalesced) ----
        const int j = c * JC + l;
        float lg;
        {
            const float4 qs0 = *(const float4*)&qsh[h][0];
            const float4 qs1 = *(const float4*)&qsh[h][4];
            const float4 qs2 = *(const float4*)&qsh[h][8];
            const float4 qs3 = *(const float4*)&qsh[h][12];
            float4 k0 = ksb[j], k1 = ksb[512 + j], k2 = ksb[1024 + j], k3 = ksb[1536 + j];
            float d0 = 0.f, d1 = 0.f;
            d0 = fmaf(qs0.x, k0.x, d0); d0 = fmaf(qs0.y, k0.y, d0);
            d0 = fmaf(qs0.z, k0.z, d0); d0 = fmaf(qs0.w, k0.w, d0);
            d1 = fmaf(qs1.x, k1.x, d1); d1 = fmaf(qs1.y, k1.y, d1);
            d1 = fmaf(qs1.z, k1.z, d1); d1 = fmaf(qs1.w, k1.w, d1);
            d0 = fmaf(qs2.x, k2.x, d0); d0 = fmaf(qs2.y, k2.y, d0);
            d0 = fmaf(qs2.z, k2.z, d0); d0 = fmaf(qs2.w, k2.w, d0);
            d1 = fmaf(qs3.x, k3.x, d1); d1 = fmaf(qs3.y, k3.y, d1);
            d1 = fmaf(qs3.z, k3.z, d1); d1 = fmaf(qs3.w, k3.w, d1);
            const float4 qp0 = *(const float4*)&qph[h][0];
            const float4 qp1 = *(const float4*)&qph[h][4];
            const float4 qp2 = *(const float4*)&qph[h][8];
            float4 P0 = kpb[j], P1 = kpb[512 + j], P2 = kpb[1024 + j];
            float e0 = 0.f, e1 = 0.f;
            e0 = fmaf(qp0.x, P0.x, e0); e0 = fmaf(qp0.y, P0.y, e0);
            e0 = fmaf(qp0.z, P0.z, e0); e0 = fmaf(qp0.w, P0.w, e0);
            e1 = fmaf(qp1.x, P1.x, e1); e1 = fmaf(qp1.y, P1.y, e1);
            e1 = fmaf(qp1.z, P1.z, e1); e1 = fmaf(qp1.w, P1.w, e1);
            e0 = fmaf(qp2.x, P2.x, e0); e0 = fmaf(qp2.y, P2.y, e0);
            e0 = fmaf(qp2.z, P2.z, e0); e0 = fmaf(qp2.w, P2.w, e0);
            float dist = qqh[h] + kkb[j] - 2.f * (e0 + e1);
            lg = fmaf(d0 + d1, SCALAR_SCALE, fmaf(coefP, dist, bias));
        }
        // ---- online softmax across the 64-lane wave, defer-rescale (T13) ----
        float cmax = lg;
#pragma unroll
        for (int off = 32; off > 0; off >>= 1) cmax = fmaxf(cmax, __shfl_xor(cmax, off));
        if (cmax > m + 6.f) {          // wave-uniform branch
            const float sc = __expf(m - cmax);
            m = cmax; lsum *= sc;
            ap0 *= sc; ap1 *= sc; ap2 *= sc; ap3 *= sc;
#pragma unroll
            for (int d = 0; d < 16; ++d) ascd[d] *= sc;
#pragma unroll
            for (int d = 0; d < 24; ++d) aptd[d] *= sc;
        }
        const float p = __expf(lg - m);
        float psum = p;
#pragma unroll
        for (int off = 32; off > 0; off >>= 1) psum += __shfl_xor(psum, off);
        lsum += psum;
        plds[h][l] = p;
        // ---- v accumulation (f4-packed coalesced loads) ----
        {
            float4 v0 = vsb[j], v1 = vsb[512 + j], v2 = vsb[1024 + j], v3 = vsb[1536 + j];
            ascd[0]  = fmaf(p, v0.x, ascd[0]);  ascd[1]  = fmaf(p, v0.y, ascd[1]);
            ascd[2]  = fmaf(p, v0.z, ascd[2]);  ascd[3]  = fmaf(p, v0.w, ascd[3]);
            ascd[4]  = fmaf(p, v1.x, ascd[4]);  ascd[5]  = fmaf(p, v1.y, ascd[5]);
            ascd[6]  = fmaf(p, v1.z, ascd[6]);  ascd[7]  = fmaf(p, v1.w, ascd[7]);
            ascd[8]  = fmaf(p, v2.x, ascd[8]);  ascd[9]  = fmaf(p, v2.y, ascd[9]);
            ascd[10] = fmaf(p, v2.z, ascd[10]); ascd[11] = fmaf(p, v2.w, ascd[11]);
            ascd[12] = fmaf(p, v3.x, ascd[12]); ascd[13] = fmaf(p, v3.y, ascd[13]);
            ascd[14] = fmaf(p, v3.z, ascd[14]); ascd[15] = fmaf(p, v3.w, ascd[15]);
#pragma unroll
            for (int g = 0; g < 6; ++g) {
                float4 w = vpb[g * 512 + j];
                aptd[4 * g + 0] = fmaf(p, w.x, aptd[4 * g + 0]);
                aptd[4 * g + 1] = fmaf(p, w.y, aptd[4 * g + 1]);
                aptd[4 * g + 2] = fmaf(p, w.z, aptd[4 * g + 2]);
                aptd[4 * g + 3] = fmaf(p, w.w, aptd[4 * g + 3]);
            }
        }
        // ---- pair accumulation: lane owns dim d=l; 32 packed column reads (2-way, free) ----
#pragma unroll
        for (int u = 0; u < 16; ++u) {
            float4 p4 = *(const float4*)&plds[h][4 * u];
            unsigned pk0 = pwt_pj[2 * u][l];
            unsigned pk1 = pwt_pj[2 * u + 1][l];
            ap0 = fmaf(p4.x, __uint_as_float(pk0 << 16),         ap0);
            ap1 = fmaf(p4.y, __uint_as_float(pk0 & 0xffff0000u), ap1);
            ap2 = fmaf(p4.z, __uint_as_float(pk1 << 16),         ap2);
            ap3 = fmaf(p4.w, __uint_as_float(pk1 & 0xffff0000u), ap3);
        }
    }

    // ---- epilogue: butterfly-reduce j-partials across 64 lanes ----
#pragma unroll
    for (int off = 32; off > 0; off >>= 1) {
#pragma unroll
        for (int d = 0; d < 16; ++d) ascd[d] += __shfl_xor(ascd[d], off);
#pragma unroll
        for (int d = 0; d < 24; ++d) aptd[d] += __shfl_xor(aptd[d], off);
    }
    const float ap = (ap0 + ap1) + (ap2 + ap3);
    const float inv_l = 1.f / lsum;
    float* fb = feats + (size_t)bi * 896;
    if (l < 16) fb[h * 16 + l] = ascd[l] * inv_l;             // m_scalar
    fb[384 + h * 64 + l] = ap * inv_l;                        // m_pair (lane owns d=l)
    const float tr0 = trans[bi * 3 + 0], tr1 = trans[bi * 3 + 1], tr2 = trans[bi * 3 + 2];
    if (l < 24) {
        const int pp = l / 3, r = l - pp * 3;
        const float c0 = aptd[pp * 3 + 0] * inv_l - tr0;
        const float c1 = aptd[pp * 3 + 1] * inv_l - tr1;
        const float c2 = aptd[pp * 3 + 2] * inv_l - tr2;
        const float* Rm = rot + (size_t)bi * 9 + r * 3;       // R[r][c]
        fb[128 + h * 24 + pp * 3 + r] = fmaf(c0, Rm[0], fmaf(c1, Rm[1], c2 * Rm[2]));
    }
    if (l < 8) {
        const float c0 = aptd[l * 3 + 0] * inv_l - tr0;
        const float c1 = aptd[l * 3 + 1] * inv_l - tr1;
        const float c2 = aptd[l * 3 + 2] * inv_l - tr2;
        fb[320 + h * 8 + l] = sqrtf(fmaf(c0, c0, fmaf(c1, c1, fmaf(c2, c2, EPSV))));
    }
}

// ---------------- output projection: 4 tokens x 192-col half per block (r7-proven) ----------------
__global__ __launch_bounds__(256) void k_out(
    const float* __restrict__ feats, const float* __restrict__ Wout,
    const float* __restrict__ bout, float* __restrict__ out)
{
    __shared__ float fl[4][896];
    const int t = threadIdx.x;
    const int tile = blockIdx.x >> 1;
    const int half = blockIdx.x & 1;
    const int tok0 = tile * 4;
    {
        const float4* src = (const float4*)(feats + (size_t)tok0 * 896);
        float4* dst = (float4*)&fl[0][0];
        dst[t] = src[t];
        dst[t + 256] = src[t + 256];
        dst[t + 512] = src[t + 512];
        if (t < 128) dst[t + 768] = src[t + 768];   // 896 float4 total
    }
    __syncthreads();
    const int tok = t >> 6, l = t & 63;
    const int c0 = 192 * half;
    float acc0 = 0.f, acc1 = 0.f, acc2 = 0.f;
#pragma unroll 8
    for (int dd = 0; dd < 896; ++dd) {
        float fv = fl[tok][dd];
        const float* wr = Wout + (size_t)dd * 384 + c0;
        acc0 = fmaf(fv, wr[l], acc0);
        acc1 = fmaf(fv, wr[l + 64], acc1);
        acc2 = fmaf(fv, wr[l + 128], acc2);
    }
    float* ob = out + (size_t)(tok0 + tok) * 384 + c0;
    ob[l]       = acc0 + bout[c0 + l];
    ob[l + 64]  = acc1 + bout[c0 + l + 64];
    ob[l + 128] = acc2 + bout[c0 + l + 128];
}

extern "C" void kernel_launch(void* const* d_in, const int* in_sizes, int n_in,
                              void* d_out, int out_size, void* d_ws, size_t ws_size,
                              hipStream_t stream) {
    const float* x        = (const float*)d_in[0];
    const float* pairw    = (const float*)d_in[1];
    const float* rot      = (const float*)d_in[2];
    const float* trans    = (const float*)d_in[3];
    const int*   pos      = (const int*)d_in[4];
    const float* Wq_s     = (const float*)d_in[6];
    const float* Wk_s     = (const float*)d_in[7];
    const float* Wv_s     = (const float*)d_in[8];
    const float* Wq_p     = (const float*)d_in[9];
    const float* Wk_p     = (const float*)d_in[10];
    const float* Wv_p     = (const float*)d_in[11];
    const float* pweights = (const float*)d_in[12];
    const float* Wpair    = (const float*)d_in[13];
    const float* bpair    = (const float*)d_in[14];
    const float* Wout     = (const float*)d_in[15];
    const float* bout     = (const float*)d_in[16];
    float* out = (float*)d_out;

    float* ws = (float*)d_ws;
    float* cos_t = ws;   ws += 4096;
    float* sin_t = ws;   ws += 4096;
    float* qsg = ws;     ws += BB * HH * NN * 16;
    float* qpg = ws;     ws += BB * HH * NN * 12;
    float* qqg = ws;     ws += BB * HH * NN;
    float4* kst = (float4*)ws; ws += BB * HH * NN * 16;   // [bh][4][N] f4
    float* kpt = ws;     ws += BB * HH * NN * 12;         // [bh][3][N] f4
    float* kkg = ws;     ws += BB * HH * NN;
    float4* vst = (float4*)ws; ws += BB * HH * NN * 16;   // [bh][4][N] f4
    float* vpt = ws;     ws += BB * HH * NN * 24;         // [bh][6][N] f4
    float* feats = ws;   ws += BB * NN * 896;

    k_rope<<<2, 256, 0, stream>>>(cos_t, sin_t);
    k_proj<<<(BB * NN) / 8 * 2, 256, 0, stream>>>(x, rot, trans, pos,
        Wq_s, Wk_s, Wv_s, Wq_p, Wk_p, Wv_p, cos_t, sin_t,
        qsg, qpg, qqg, kst, kpt, kkg, vst, vpt);
    k_attn<<<BB * NN, 512, 0, stream>>>(pairw, rot, trans, Wpair, bpair, pweights,
        qsg, qpg, qqg, kst, (const float4*)kpt, kkg, vst, (const float4*)vpt, feats);
    k_out<<<(BB * NN) / 4 * 2, 256, 0, stream>>>(feats, Wout, bout, out);

    (void)in_sizes; (void)n_in; (void)out_size; (void)ws_size;
}

// Round 15
// 351.631 us; speedup vs baseline: 1.2460x; 1.0198x over previous
//
#include <hip/hip_runtime.h>
#include <math.h>

#define BB 4
#define NN 512
#define DIMX 384
#define HH 8
#define PDD 64
#define JC 64

static constexpr float EPSV = 1e-8f;
static constexpr float SCALAR_SCALE = 0.14433756729740643f;  // (3*16)^-0.5
static constexpr float POINT_SCALE  = 0.1360827634879543f;   // (3*4*4.5)^-0.5
static constexpr float PAIR_SCALE   = 0.5773502691896258f;   // 3^-0.5

static __device__ __forceinline__ unsigned pack_bf16_rn(float a, float b) {
    unsigned ua = (__float_as_uint(a) + 0x8000u) >> 16;
    unsigned ub = (__float_as_uint(b) + 0x8000u) & 0xffff0000u;
    return ua | ub;
}

// ---------------- rope table ----------------
__global__ void k_rope(float* __restrict__ cos_t, float* __restrict__ sin_t) {
    int n = blockIdx.x * blockDim.x + threadIdx.x;
    if (n >= NN) return;
#pragma unroll
    for (int i = 0; i < 8; ++i) {
        float invf = powf(10000.0f, -(float)i / 8.0f);
        float f = (float)n * invf;
        cos_t[n * 8 + i] = cosf(f);
        sin_t[n * 8 + i] = sinf(f);
    }
}

// ---------------- projections + transforms (column-half split) ----------------
__global__ __launch_bounds__(256) void k_proj(
    const float* __restrict__ x, const float* __restrict__ rot,
    const float* __restrict__ trans, const int* __restrict__ pos_ids,
    const float* __restrict__ Wq_s, const float* __restrict__ Wk_s, const float* __restrict__ Wv_s,
    const float* __restrict__ Wq_p, const float* __restrict__ Wk_p, const float* __restrict__ Wv_p,
    const float* __restrict__ cos_t, const float* __restrict__ sin_t,
    float* __restrict__ qsg, float* __restrict__ qpg, float* __restrict__ qqg,
    float4* __restrict__ kst, float* __restrict__ kpt, float* __restrict__ kkg,
    float4* __restrict__ vst, float* __restrict__ vpt)
{
    __shared__ float xl[8][DIMX];
    __shared__ float raw[8][384];
    const int t = threadIdx.x;
    const int tile = blockIdx.x >> 1;
    const int half = blockIdx.x & 1;
    const int tok0 = tile * 8;

    {
        const float4* xg = (const float4*)(x + (size_t)tok0 * DIMX);
        float4* xl4 = (float4*)&xl[0][0];
#pragma unroll
        for (int k = 0; k < 3; ++k) xl4[t + 256 * k] = xg[t + 256 * k];
    }
    __syncthreads();

    const int tok = t >> 5, l = t & 31;
    {
        float4 acc[3];
        const float* wb[3];
        int st[3];
#pragma unroll
        for (int m = 0; m < 3; ++m) {
            int f = l + 32 * m + 96 * half;
            const float* w; int out, c;
            if (f < 32)       { w = Wq_s; out = 128; c = 4 * f; }
            else if (f < 64)  { w = Wk_s; out = 128; c = 4 * f - 128; }
            else if (f < 96)  { w = Wv_s; out = 128; c = 4 * f - 256; }
            else if (f < 120) { w = Wq_p; out = 96;  c = 4 * f - 384; }
            else if (f < 144) { w = Wk_p; out = 96;  c = 4 * f - 480; }
            else              { w = Wv_p; out = 192; c = 4 * f - 576; }
            wb[m] = w + c; st[m] = out;
            acc[m] = make_float4(0.f, 0.f, 0.f, 0.f);
        }
        for (int dd = 0; dd < DIMX; ++dd) {
            float xv = xl[tok][dd];
#pragma unroll
            for (int m = 0; m < 3; ++m) {
                float4 wv = *(const float4*)(wb[m] + (size_t)dd * st[m]);
                acc[m].x = fmaf(xv, wv.x, acc[m].x);
                acc[m].y = fmaf(xv, wv.y, acc[m].y);
                acc[m].z = fmaf(xv, wv.z, acc[m].z);
                acc[m].w = fmaf(xv, wv.w, acc[m].w);
            }
        }
#pragma unroll
        for (int m = 0; m < 3; ++m)
            *(float4*)&raw[tok][4 * (l + 32 * m)] = acc[m];
    }
    __syncthreads();

    const int h = l >> 2, q = l & 3;
    const int n_g = tok0 + tok;
    const int b = n_g / NN;
    const int nloc = n_g - b * NN;
    const int bh = b * HH + h;
    const size_t rowi = (size_t)bh * NN + nloc;

    if (half == 0) {
        const int pos = pos_ids[n_g];
        float qv[4], kv[4], vv[4];
#pragma unroll
        for (int dd0 = 0; dd0 < 4; ++dd0) {
            int dd = q * 4 + dd0;
            int i8 = dd & 7;
            float c = cos_t[pos * 8 + i8], s = sin_t[pos * 8 + i8];
            float xq = raw[tok][h * 16 + dd];
            float rq = (dd < 8) ? -raw[tok][h * 16 + dd + 8] : raw[tok][h * 16 + dd - 8];
            qv[dd0] = fmaf(xq, c, rq * s);
            float xk = raw[tok][128 + h * 16 + dd];
            float rk = (dd < 8) ? -raw[tok][128 + h * 16 + dd + 8] : raw[tok][128 + h * 16 + dd - 8];
            kv[dd0] = fmaf(xk, c, rk * s);
            vv[dd0] = raw[tok][256 + h * 16 + dd];
        }
        *(float4*)&qsg[rowi * 16 + q * 4] = make_float4(qv[0], qv[1], qv[2], qv[3]);
        kst[(size_t)bh * 2048 + q * 512 + nloc] = make_float4(kv[0], kv[1], kv[2], kv[3]);
        vst[(size_t)bh * 2048 + q * 512 + nloc] = make_float4(vv[0], vv[1], vv[2], vv[3]);
    } else {
        const float* Rm = rot + (size_t)n_g * 9;
        const float trv[3] = {trans[n_g * 3 + 0], trans[n_g * 3 + 1], trans[n_g * 3 + 2]};
        float qqp = 0.f, kkp = 0.f;
        {
            float pc[3], kc[3];
#pragma unroll
            for (int c = 0; c < 3; ++c) {
                pc[c] = raw[tok][h * 12 + q * 3 + c];
                kc[c] = raw[tok][96 + h * 12 + q * 3 + c];
            }
#pragma unroll
            for (int r = 0; r < 3; ++r) {
                float vq = trv[r], vk = trv[r];
#pragma unroll
                for (int c = 0; c < 3; ++c) {
                    vq = fmaf(pc[c], Rm[c * 3 + r], vq);
                    vk = fmaf(kc[c], Rm[c * 3 + r], vk);
                }
                qpg[rowi * 12 + q * 3 + r] = vq;
                int d = q * 3 + r;   // 0..11
                kpt[(size_t)bh * 6144 + (d >> 2) * 2048 + nloc * 4 + (d & 3)] = vk;
                qqp = fmaf(vq, vq, qqp);
                kkp = fmaf(vk, vk, kkp);
            }
        }
        qqp += __shfl_xor(qqp, 1); qqp += __shfl_xor(qqp, 2);
        kkp += __shfl_xor(kkp, 1); kkp += __shfl_xor(kkp, 2);
        if (q == 0) { qqg[rowi] = qqp; kkg[rowi] = kkp; }
#pragma unroll
        for (int pp = 0; pp < 2; ++pp) {
            int p = q + 4 * pp;
            float pc[3];
#pragma unroll
            for (int c = 0; c < 3; ++c) pc[c] = raw[tok][192 + h * 24 + p * 3 + c];
#pragma unroll
            for (int r = 0; r < 3; ++r) {
                float v = trv[r];
#pragma unroll
                for (int c = 0; c < 3; ++c) v = fmaf(pc[c], Rm[c * 3 + r], v);
                int d = p * 3 + r;   // 0..23
                vpt[(size_t)bh * 12288 + (d >> 2) * 2048 + nloc * 4 + (d & 3)] = v;
            }
        }
    }
}

// ---------------- fused attention: 512 threads, wave = head, lane = j ----------------
// r14 structure with DOUBLE-BUFFERED bf16-packed pw tile -> 2 barriers/chunk (was 3):
// phase1 {next-chunk loads || bias partials from buf[cur] -> parts || stage buf[nxt]} BAR
// phase2 {read parts -> bias; logit; softmax; v-accum; pair-accum from buf[cur]} BAR
__global__ __launch_bounds__(512, 2) void k_attn(
    const float* __restrict__ pairw,
    const float* __restrict__ rot, const float* __restrict__ trans,
    const float* __restrict__ Wpair, const float* __restrict__ bpair,
    const float* __restrict__ pweights,
    const float* __restrict__ qsg, const float* __restrict__ qpg, const float* __restrict__ qqg,
    const float4* __restrict__ kst, const float4* __restrict__ kpt, const float* __restrict__ kkg,
    const float4* __restrict__ vst, const float4* __restrict__ vpt,
    float* __restrict__ feats)
{
    __shared__ unsigned pwt_pj[2][32][66]; // bf16-packed pw tile, double-buffered (16.5KB)
    __shared__ float parts[8][HH][JC];     // [slice][head][j] bias partials (16KB)
    __shared__ float Wl[512];              // W_pair [d][h] row-major
    __shared__ float plds[HH][JC];
    __shared__ float qsh[HH][16];
    __shared__ float qph[HH][12];
    __shared__ float qqh[HH];

    const int t = threadIdx.x;
    const int bi = blockIdx.x;
    const int b = bi >> 9;
    const int h = t >> 6, l = t & 63;  // wave = head, lane = j-in-chunk

    Wl[t] = Wpair[t];

    const int bh = b * HH + h;
    const size_t rowq = (size_t)bh * NN + (bi & 511);
    if (l < 16) qsh[h][l] = qsg[rowq * 16 + l];
    if (l < 12) qph[h][l] = qpg[rowq * 12 + l];
    if (l == 0) qqh[h] = qqg[rowq];

    const float coefP = -0.5f * log1pf(__expf(pweights[h])) * POINT_SCALE;
    const float bp_h = bpair[h];

    const float4* ksb = kst + (size_t)bh * 2048;   // [4][512] f4
    const float4* vsb = vst + (size_t)bh * 2048;
    const float4* kpb = kpt + (size_t)bh * 1536;   // [3][512] f4
    const float4* vpb = vpt + (size_t)bh * 3072;   // [6][512] f4
    const float*  kkb = kkg + (size_t)bh * 512;

    const float4* pwsrc = (const float4*)(pairw + (size_t)bi * NN * PDD);
    const int j2 = t >> 4, q4 = t & 15;   // staging ownership

    // prologue: stage chunk 0 into buffer 0
    {
        float4 va = pwsrc[(size_t)(2 * j2) * 16 + q4];
        float4 vb = pwsrc[(size_t)(2 * j2 + 1) * 16 + q4];
        *(uint2*)&pwt_pj[0][j2][q4 * 4]     = make_uint2(pack_bf16_rn(va.x, vb.x), pack_bf16_rn(va.y, vb.y));
        *(uint2*)&pwt_pj[0][j2][q4 * 4 + 2] = make_uint2(pack_bf16_rn(va.z, vb.z), pack_bf16_rn(va.w, vb.w));
    }
    __syncthreads();

    float m = -3.0e38f, lsum = 0.f;
    float ap0 = 0.f, ap1 = 0.f, ap2 = 0.f, ap3 = 0.f;
    float ascd[16], aptd[24];
#pragma unroll
    for (int d = 0; d < 16; ++d) ascd[d] = 0.f;
#pragma unroll
    for (int d = 0; d < 24; ++d) aptd[d] = 0.f;

    for (int c = 0; c < NN / JC; ++c) {
        const int cur = c & 1, nxt = cur ^ 1;
        const bool more = (c < NN / JC - 1);
        // issue next-chunk global loads (consumed by LDS writes at the end of this phase)
        float4 va, vb;
        if (more) {
            va = pwsrc[(size_t)(c + 1) * 1024 + (size_t)(2 * j2) * 16 + q4];
            vb = pwsrc[(size_t)(c + 1) * 1024 + (size_t)(2 * j2 + 1) * 16 + q4];
        }
        {   // bias partials: slice = h, row j = l (packed row l>>1, half l&1)
            const int j2l = l >> 1;
            const bool hi = (l & 1) != 0;
            uint2 q0 = *(const uint2*)&pwt_pj[cur][j2l][8 * h + 0];
            uint2 q1 = *(const uint2*)&pwt_pj[cur][j2l][8 * h + 2];
            uint2 q2 = *(const uint2*)&pwt_pj[cur][j2l][8 * h + 4];
            uint2 q3 = *(const uint2*)&pwt_pj[cur][j2l][8 * h + 6];
            unsigned vv[8] = {q0.x, q0.y, q1.x, q1.y, q2.x, q2.y, q3.x, q3.y};
            float pv[8];
#pragma unroll
            for (int k = 0; k < 8; ++k)
                pv[k] = __uint_as_float(hi ? (vv[k] & 0xffff0000u) : (vv[k] << 16));
            float ps[8];
#pragma unroll
            for (int hh = 0; hh < 8; ++hh) ps[hh] = 0.f;
#pragma unroll
            for (int k = 0; k < 8; ++k) {
                const float pk = pv[k];
                const float4 w0 = *(const float4*)&Wl[(8 * h + k) * 8];
                const float4 w1 = *(const float4*)&Wl[(8 * h + k) * 8 + 4];
                ps[0] = fmaf(pk, w0.x, ps[0]); ps[1] = fmaf(pk, w0.y, ps[1]);
                ps[2] = fmaf(pk, w0.z, ps[2]); ps[3] = fmaf(pk, w0.w, ps[3]);
                ps[4] = fmaf(pk, w1.x, ps[4]); ps[5] = fmaf(pk, w1.y, ps[5]);
                ps[6] = fmaf(pk, w1.z, ps[6]); ps[7] = fmaf(pk, w1.w, ps[7]);
            }
#pragma unroll
            for (int hh = 0; hh < 8; ++hh) parts[h][hh][l] = ps[hh];
        }
        // stage next chunk into the other buffer (its last readers were fenced by prev end-BAR)
        if (more) {
            *(uint2*)&pwt_pj[nxt][j2][q4 * 4]     = make_uint2(pack_bf16_rn(va.x, vb.x), pack_bf16_rn(va.y, vb.y));
            *(uint2*)&pwt_pj[nxt][j2][q4 * 4 + 2] = make_uint2(pack_bf16_rn(va.z, vb.z), pack_bf16_rn(va.w, vb.w));
        }
        __syncthreads();   // BAR: parts ready, buf[nxt] staged
        float bs = 0.f;
#pragma unroll
        for (int s2 = 0; s2 < 8; ++s2) bs += parts[s2][h][l];
        const float bias = (bs + bp_h) * PAIR_SCALE;
        // ---- logit (f4-packed d-major loads, all stride-1 coalesced) ----
        const int j = c * JC + l;
        float lg;
        {
            const float4 qs0 = *(const float4*)&qsh[h][0];
            const float4 qs1 = *(const float4*)&qsh[h][4];
            const float4 qs2 = *(const float4*)&qsh[h][8];
            const float4 qs3 = *(const float4*)&qsh[h][12];
            float4 k0 = ksb[j], k1 = ksb[512 + j], k2 = ksb[1024 + j], k3 = ksb[1536 + j];
            float d0 = 0.f, d1 = 0.f;
            d0 = fmaf(qs0.x, k0.x, d0); d0 = fmaf(qs0.y, k0.y, d0);
            d0 = fmaf(qs0.z, k0.z, d0); d0 = fmaf(qs0.w, k0.w, d0);
            d1 = fmaf(qs1.x, k1.x, d1); d1 = fmaf(qs1.y, k1.y, d1);
            d1 = fmaf(qs1.z, k1.z, d1); d1 = fmaf(qs1.w, k1.w, d1);
            d0 = fmaf(qs2.x, k2.x, d0); d0 = fmaf(qs2.y, k2.y, d0);
            d0 = fmaf(qs2.z, k2.z, d0); d0 = fmaf(qs2.w, k2.w, d0);
            d1 = fmaf(qs3.x, k3.x, d1); d1 = fmaf(qs3.y, k3.y, d1);
            d1 = fmaf(qs3.z, k3.z, d1); d1 = fmaf(qs3.w, k3.w, d1);
            const float4 qp0 = *(const float4*)&qph[h][0];
            const float4 qp1 = *(const float4*)&qph[h][4];
            const float4 qp2 = *(const float4*)&qph[h][8];
            float4 P0 = kpb[j], P1 = kpb[512 + j], P2 = kpb[1024 + j];
            float e0 = 0.f, e1 = 0.f;
            e0 = fmaf(qp0.x, P0.x, e0); e0 = fmaf(qp0.y, P0.y, e0);
            e0 = fmaf(qp0.z, P0.z, e0); e0 = fmaf(qp0.w, P0.w, e0);
            e1 = fmaf(qp1.x, P1.x, e1); e1 = fmaf(qp1.y, P1.y, e1);
            e1 = fmaf(qp1.z, P1.z, e1); e1 = fmaf(qp1.w, P1.w, e1);
            e0 = fmaf(qp2.x, P2.x, e0); e0 = fmaf(qp2.y, P2.y, e0);
            e0 = fmaf(qp2.z, P2.z, e0); e0 = fmaf(qp2.w, P2.w, e0);
            float dist = qqh[h] + kkb[j] - 2.f * (e0 + e1);
            lg = fmaf(d0 + d1, SCALAR_SCALE, fmaf(coefP, dist, bias));
        }
        // ---- online softmax across the 64-lane wave, defer-rescale (T13) ----
        float cmax = lg;
#pragma unroll
        for (int off = 32; off > 0; off >>= 1) cmax = fmaxf(cmax, __shfl_xor(cmax, off));
        if (cmax > m + 6.f) {          // wave-uniform branch
            const float sc = __expf(m - cmax);
            m = cmax; lsum *= sc;
            ap0 *= sc; ap1 *= sc; ap2 *= sc; ap3 *= sc;
#pragma unroll
            for (int d = 0; d < 16; ++d) ascd[d] *= sc;
#pragma unroll
            for (int d = 0; d < 24; ++d) aptd[d] *= sc;
        }
        const float p = __expf(lg - m);
        float psum = p;
#pragma unroll
        for (int off = 32; off > 0; off >>= 1) psum += __shfl_xor(psum, off);
        lsum += psum;
        plds[h][l] = p;
        // ---- v accumulation (f4-packed coalesced loads) ----
        {
            float4 v0 = vsb[j], v1 = vsb[512 + j], v2 = vsb[1024 + j], v3 = vsb[1536 + j];
            ascd[0]  = fmaf(p, v0.x, ascd[0]);  ascd[1]  = fmaf(p, v0.y, ascd[1]);
            ascd[2]  = fmaf(p, v0.z, ascd[2]);  ascd[3]  = fmaf(p, v0.w, ascd[3]);
            ascd[4]  = fmaf(p, v1.x, ascd[4]);  ascd[5]  = fmaf(p, v1.y, ascd[5]);
            ascd[6]  = fmaf(p, v1.z, ascd[6]);  ascd[7]  = fmaf(p, v1.w, ascd[7]);
            ascd[8]  = fmaf(p, v2.x, ascd[8]);  ascd[9]  = fmaf(p, v2.y, ascd[9]);
            ascd[10] = fmaf(p, v2.z, ascd[10]); ascd[11] = fmaf(p, v2.w, ascd[11]);
            ascd[12] = fmaf(p, v3.x, ascd[12]); ascd[13] = fmaf(p, v3.y, ascd[13]);
            ascd[14] = fmaf(p, v3.z, ascd[14]); ascd[15] = fmaf(p, v3.w, ascd[15]);
#pragma unroll
            for (int g = 0; g < 6; ++g) {
                float4 w = vpb[g * 512 + j];
                aptd[4 * g + 0] = fmaf(p, w.x, aptd[4 * g + 0]);
                aptd[4 * g + 1] = fmaf(p, w.y, aptd[4 * g + 1]);
                aptd[4 * g + 2] = fmaf(p, w.z, aptd[4 * g + 2]);
                aptd[4 * g + 3] = fmaf(p, w.w, aptd[4 * g + 3]);
            }
        }
        // ---- pair accumulation: lane owns dim d=l; 32 packed column reads (2-way, free) ----
#pragma unroll
        for (int u = 0; u < 16; ++u) {
            float4 p4 = *(const float4*)&plds[h][4 * u];
            unsigned pk0 = pwt_pj[cur][2 * u][l];
            unsigned pk1 = pwt_pj[cur][2 * u + 1][l];
            ap0 = fmaf(p4.x, __uint_as_float(pk0 << 16),         ap0);
            ap1 = fmaf(p4.y, __uint_as_float(pk0 & 0xffff0000u), ap1);
            ap2 = fmaf(p4.z, __uint_as_float(pk1 << 16),         ap2);
            ap3 = fmaf(p4.w, __uint_as_float(pk1 & 0xffff0000u), ap3);
        }
        __syncthreads();   // end-BAR: fences buf[cur] + parts reads before next chunk rewrites
    }

    // ---- epilogue: butterfly-reduce j-partials across 64 lanes ----
#pragma unroll
    for (int off = 32; off > 0; off >>= 1) {
#pragma unroll
        for (int d = 0; d < 16; ++d) ascd[d] += __shfl_xor(ascd[d], off);
#pragma unroll
        for (int d = 0; d < 24; ++d) aptd[d] += __shfl_xor(aptd[d], off);
    }
    const float ap = (ap0 + ap1) + (ap2 + ap3);
    const float inv_l = 1.f / lsum;
    float* fb = feats + (size_t)bi * 896;
    if (l < 16) fb[h * 16 + l] = ascd[l] * inv_l;             // m_scalar
    fb[384 + h * 64 + l] = ap * inv_l;                        // m_pair (lane owns d=l)
    const float tr0 = trans[bi * 3 + 0], tr1 = trans[bi * 3 + 1], tr2 = trans[bi * 3 + 2];
    if (l < 24) {
        const int pp = l / 3, r = l - pp * 3;
        const float c0 = aptd[pp * 3 + 0] * inv_l - tr0;
        const float c1 = aptd[pp * 3 + 1] * inv_l - tr1;
        const float c2 = aptd[pp * 3 + 2] * inv_l - tr2;
        const float* Rm = rot + (size_t)bi * 9 + r * 3;       // R[r][c]
        fb[128 + h * 24 + pp * 3 + r] = fmaf(c0, Rm[0], fmaf(c1, Rm[1], c2 * Rm[2]));
    }
    if (l < 8) {
        const float c0 = aptd[l * 3 + 0] * inv_l - tr0;
        const float c1 = aptd[l * 3 + 1] * inv_l - tr1;
        const float c2 = aptd[l * 3 + 2] * inv_l - tr2;
        fb[320 + h * 8 + l] = sqrtf(fmaf(c0, c0, fmaf(c1, c1, fmaf(c2, c2, EPSV))));
    }
}

// ---------------- output projection: 4 tokens x 192-col half per block (r7-proven) ----------------
__global__ __launch_bounds__(256) void k_out(
    const float* __restrict__ feats, const float* __restrict__ Wout,
    const float* __restrict__ bout, float* __restrict__ out)
{
    __shared__ float fl[4][896];
    const int t = threadIdx.x;
    const int tile = blockIdx.x >> 1;
    const int half = blockIdx.x & 1;
    const int tok0 = tile * 4;
    {
        const float4* src = (const float4*)(feats + (size_t)tok0 * 896);
        float4* dst = (float4*)&fl[0][0];
        dst[t] = src[t];
        dst[t + 256] = src[t + 256];
        dst[t + 512] = src[t + 512];
        if (t < 128) dst[t + 768] = src[t + 768];   // 896 float4 total
    }
    __syncthreads();
    const int tok = t >> 6, l = t & 63;
    const int c0 = 192 * half;
    float acc0 = 0.f, acc1 = 0.f, acc2 = 0.f;
#pragma unroll 8
    for (int dd = 0; dd < 896; ++dd) {
        float fv = fl[tok][dd];
        const float* wr = Wout + (size_t)dd * 384 + c0;
        acc0 = fmaf(fv, wr[l], acc0);
        acc1 = fmaf(fv, wr[l + 64], acc1);
        acc2 = fmaf(fv, wr[l + 128], acc2);
    }
    float* ob = out + (size_t)(tok0 + tok) * 384 + c0;
    ob[l]       = acc0 + bout[c0 + l];
    ob[l + 64]  = acc1 + bout[c0 + l + 64];
    ob[l + 128] = acc2 + bout[c0 + l + 128];
}

extern "C" void kernel_launch(void* const* d_in, const int* in_sizes, int n_in,
                              void* d_out, int out_size, void* d_ws, size_t ws_size,
                              hipStream_t stream) {
    const float* x        = (const float*)d_in[0];
    const float* pairw    = (const float*)d_in[1];
    const float* rot      = (const float*)d_in[2];
    const float* trans    = (const float*)d_in[3];
    const int*   pos      = (const int*)d_in[4];
    const float* Wq_s     = (const float*)d_in[6];
    const float* Wk_s     = (const float*)d_in[7];
    const float* Wv_s     = (const float*)d_in[8];
    const float* Wq_p     = (const float*)d_in[9];
    const float* Wk_p     = (const float*)d_in[10];
    const float* Wv_p     = (const float*)d_in[11];
    const float* pweights = (const float*)d_in[12];
    const float* Wpair    = (const float*)d_in[13];
    const float* bpair    = (const float*)d_in[14];
    const float* Wout     = (const float*)d_in[15];
    const float* bout     = (const float*)d_in[16];
    float* out = (float*)d_out;

    float* ws = (float*)d_ws;
    float* cos_t = ws;   ws += 4096;
    float* sin_t = ws;   ws += 4096;
    float* qsg = ws;     ws += BB * HH * NN * 16;
    float* qpg = ws;     ws += BB * HH * NN * 12;
    float* qqg = ws;     ws += BB * HH * NN;
    float4* kst = (float4*)ws; ws += BB * HH * NN * 16;   // [bh][4][N] f4
    float* kpt = ws;     ws += BB * HH * NN * 12;         // [bh][3][N] f4
    float* kkg = ws;     ws += BB * HH * NN;
    float4* vst = (float4*)ws; ws += BB * HH * NN * 16;   // [bh][4][N] f4
    float* vpt = ws;     ws += BB * HH * NN * 24;         // [bh][6][N] f4
    float* feats = ws;   ws += BB * NN * 896;

    k_rope<<<2, 256, 0, stream>>>(cos_t, sin_t);
    k_proj<<<(BB * NN) / 8 * 2, 256, 0, stream>>>(x, rot, trans, pos,
        Wq_s, Wk_s, Wv_s, Wq_p, Wk_p, Wv_p, cos_t, sin_t,
        qsg, qpg, qqg, kst, kpt, kkg, vst, vpt);
    k_attn<<<BB * NN, 512, 0, stream>>>(pairw, rot, trans, Wpair, bpair, pweights,
        qsg, qpg, qqg, kst, (const float4*)kpt, kkg, vst, (const float4*)vpt, feats);
    k_out<<<(BB * NN) / 4 * 2, 256, 0, stream>>>(feats, Wout, bout, out);

    (void)in_sizes; (void)n_in; (void)out_size; (void)ws_size;
}